// Round 1
// baseline (698.090 us; speedup 1.0000x reference)
//
#include <hip/hip_runtime.h>
#include <hip/hip_bf16.h>
#include <cstdint>

// ---------------------------------------------------------------------------
// SAGENet (2-layer SAGEConv 'pool' aggregator), fp32 SIMT baseline.
// Shapes (fixed by problem): F=128, N0=409600, N1=40960, N2=4096,
// E0=409600, E1=40960.
// Pipeline:
//   m0 = relu(h_item @ W_pool0 + b_pool0)              [N0,128]  (bf16 store)
//   agg0 = segment_max(m0[esrc0], edst0, N1)           [N1,128]  (fp32, atomics)
//   h  = relu(h_item[:N1]@W_self0 + agg0@W_neigh0 + bias0)  [N1,256]
//   m1 = relu(h @ W_pool1 + b_pool1)                   [N1,256]  (bf16 store)
//   agg1 = segment_max(m1[esrc1], edst1, N2)           [N2,256]
//   out = h_item_dst + h[:N2]@W_self1 + agg1@W_neigh1 + bias1  [N2,128]
// segment_max of relu'd (>=0) values with 0-init == jnp semantics
// (empty segment -> -inf -> where(isfinite)->0; we init 0 and max >=0 vals).
// atomicMax on int-punned fp32 is order-correct for values >= 0.
// ---------------------------------------------------------------------------

typedef unsigned int uint32;

__device__ __forceinline__ float bf_to_f(unsigned short u) {
    union { uint32 u; float f; } cv; cv.u = ((uint32)u) << 16; return cv.f;
}
__device__ __forceinline__ unsigned short f_to_bf(float f) {
    union { float f; uint32 u; } cv; cv.f = f;
    uint32 u = cv.u;
    uint32 r = (u + 0x7FFFu + ((u >> 16) & 1u)) >> 16;  // RNE
    return (unsigned short)r;
}

#define TILE_BM 64
#define TILE_BN 128
#define TILE_BK 32

// C[M,N] = act( A0@W0 (+ A1@W1) + bias (+ addsrc) ), optional bf16 output.
// A0:[M,K0], A1:[M,K1], W0:[K0,N], W1:[K1,N]. M%64==0, N%128==0, K%32==0.
template<bool HAS_A1, bool RELU, bool BF16_OUT, bool HAS_ADD>
__global__ __launch_bounds__(256, 2) void gemm_fused(
    const float* __restrict__ A0, int K0, const float* __restrict__ W0,
    const float* __restrict__ A1, int K1, const float* __restrict__ W1,
    const float* __restrict__ bias, const float* __restrict__ addsrc,
    void* __restrict__ Cout, int M, int N)
{
    __shared__ float As[TILE_BK][TILE_BM + 4];   // transposed A tile, stride 68 (16B-aligned)
    __shared__ float Ws[TILE_BK][TILE_BN + 4];   // W tile, stride 132 (16B-aligned)

    const int tid = threadIdx.x;
    const int tx = tid & 15;        // 16 col-threads * 8 cols
    const int ty = tid >> 4;        // 16 row-threads * 4 rows
    const int row0 = blockIdx.x * TILE_BM;
    const int col0 = blockIdx.y * TILE_BN;

    float acc[4][8];
    #pragma unroll
    for (int i = 0; i < 4; ++i)
        #pragma unroll
        for (int j = 0; j < 8; ++j) acc[i][j] = 0.f;

    auto run_seg = [&](const float* __restrict__ A, int K, const float* __restrict__ W) {
        for (int kk = 0; kk < K; kk += TILE_BK) {
            __syncthreads();   // protect LDS reads of previous tile
            // ---- load A tile 64x32, store transposed As[k][m]
            #pragma unroll
            for (int s = 0; s < 2; ++s) {
                int idx = tid + s * 256;            // 0..511
                int r   = idx >> 3;                 // 0..63
                int kq  = idx & 7;                  // 0..7  (float4 within 32 k's)
                float4 v = *(const float4*)(A + (size_t)(row0 + r) * K + kk + kq * 4);
                As[kq * 4 + 0][r] = v.x;
                As[kq * 4 + 1][r] = v.y;
                As[kq * 4 + 2][r] = v.z;
                As[kq * 4 + 3][r] = v.w;
            }
            // ---- load W tile 32x128
            #pragma unroll
            for (int s = 0; s < 4; ++s) {
                int idx = tid + s * 256;            // 0..1023
                int kr  = idx >> 5;                 // 0..31
                int cq  = idx & 31;                 // 0..31 (float4 within 128 cols)
                float4 v = *(const float4*)(W + (size_t)(kk + kr) * N + col0 + cq * 4);
                *(float4*)&Ws[kr][cq * 4] = v;
            }
            __syncthreads();
            // ---- inner product
            #pragma unroll
            for (int k = 0; k < TILE_BK; ++k) {
                float4 av = *(const float4*)&As[k][ty * 4];
                float4 w0 = *(const float4*)&Ws[k][tx * 8];
                float4 w1 = *(const float4*)&Ws[k][tx * 8 + 4];
                float a[4] = {av.x, av.y, av.z, av.w};
                float w[8] = {w0.x, w0.y, w0.z, w0.w, w1.x, w1.y, w1.z, w1.w};
                #pragma unroll
                for (int i = 0; i < 4; ++i)
                    #pragma unroll
                    for (int j = 0; j < 8; ++j)
                        acc[i][j] = fmaf(a[i], w[j], acc[i][j]);
            }
        }
    };

    run_seg(A0, K0, W0);
    if (HAS_A1) run_seg(A1, K1, W1);

    // ---- epilogue
    #pragma unroll
    for (int i = 0; i < 4; ++i) {
        const int r = row0 + ty * 4 + i;
        const int cbase = col0 + tx * 8;
        float out[8];
        #pragma unroll
        for (int j = 0; j < 8; ++j) {
            float v = acc[i][j] + bias[cbase + j];
            if (HAS_ADD) v += addsrc[(size_t)r * N + cbase + j];
            if (RELU) v = fmaxf(v, 0.f);
            out[j] = v;
        }
        if (BF16_OUT) {
            unsigned short us[8];
            #pragma unroll
            for (int j = 0; j < 8; ++j) us[j] = f_to_bf(out[j]);
            *(uint4*)((unsigned short*)Cout + (size_t)r * N + cbase) = *(uint4*)us;
        } else {
            float* C = (float*)Cout;
            *(float4*)(C + (size_t)r * N + cbase)     = make_float4(out[0], out[1], out[2], out[3]);
            *(float4*)(C + (size_t)r * N + cbase + 4) = make_float4(out[4], out[5], out[6], out[7]);
        }
    }
}

// Per-edge scatter-max: agg[edst[e]][:] = max(agg, m[esrc[e]][:]).
// F/2 threads per edge (each lane handles 2 bf16 feats). Values >= 0.
template<int F>
__global__ __launch_bounds__(256) void scatter_max_kernel(
    const unsigned short* __restrict__ m,   // bf16 [*, F]
    const int* __restrict__ esrc, const int* __restrict__ edst,
    int* __restrict__ agg,                  // fp32-bits [num_dst, F], pre-zeroed
    int E)
{
    constexpr int TPE = F / 2;                       // threads per edge
    constexpr int EPB = 256 / TPE;                   // edges per block
    int e = blockIdx.x * EPB + threadIdx.x / TPE;
    if (e >= E) return;
    int f2 = threadIdx.x % TPE;
    int s = esrc[e];
    int d = edst[e];
    ushort2 v2 = *(const ushort2*)(m + (size_t)s * F + 2 * f2);
    float v0 = bf_to_f(v2.x), v1 = bf_to_f(v2.y);
    int* p = agg + (size_t)d * F + 2 * f2;
    atomicMax(p,     __float_as_int(v0));
    atomicMax(p + 1, __float_as_int(v1));
}

extern "C" void kernel_launch(void* const* d_in, const int* in_sizes, int n_in,
                              void* d_out, int out_size, void* d_ws, size_t ws_size,
                              hipStream_t stream)
{
    const float* h_item     = (const float*)d_in[0];
    const float* h_item_dst = (const float*)d_in[1];
    const int*   esrc0      = (const int*)d_in[2];
    const int*   edst0      = (const int*)d_in[3];
    const int*   esrc1      = (const int*)d_in[4];
    const int*   edst1      = (const int*)d_in[5];
    // d_in[6] = num_mid (device scalar, fixed 40960 for this problem)
    const float* W_pool0  = (const float*)d_in[7];
    const float* b_pool0  = (const float*)d_in[8];
    const float* W_self0  = (const float*)d_in[9];
    const float* W_neigh0 = (const float*)d_in[10];
    const float* bias0    = (const float*)d_in[11];
    const float* W_pool1  = (const float*)d_in[12];
    const float* b_pool1  = (const float*)d_in[13];
    const float* W_self1  = (const float*)d_in[14];
    const float* W_neigh1 = (const float*)d_in[15];
    const float* bias1    = (const float*)d_in[16];

    const int F  = 128;
    const int N0 = in_sizes[0] / F;     // 409600
    const int N2 = in_sizes[1] / F;     // 4096
    const int E0 = in_sizes[2];         // 409600
    const int E1 = in_sizes[4];         // 40960
    const int N1 = 40960;               // num_mid (fixed)

    // ---- workspace carve-up (~193 MB total)
    char* ws = (char*)d_ws;
    unsigned short* m0 = (unsigned short*)ws;  ws += (size_t)N0 * F * 2;        // bf16 [N0,128]
    float* agg0        = (float*)ws;           ws += (size_t)N1 * F * 4;        // fp32 [N1,128]
    float* h           = (float*)ws;           ws += (size_t)N1 * 2 * F * 4;    // fp32 [N1,256]
    unsigned short* m1 = (unsigned short*)ws;  ws += (size_t)N1 * 2 * F * 2;    // bf16 [N1,256]
    float* agg1        = (float*)ws;           ws += (size_t)N2 * 2 * F * 4;    // fp32 [N2,256]

    hipMemsetAsync(agg0, 0, (size_t)N1 * F * 4, stream);
    hipMemsetAsync(agg1, 0, (size_t)N2 * 2 * F * 4, stream);

    // 1) m0 = relu(h_item @ W_pool0 + b_pool0) -> bf16
    {
        dim3 g(N0 / TILE_BM, F / TILE_BN);
        gemm_fused<false, true, true, false><<<g, 256, 0, stream>>>(
            h_item, F, W_pool0, nullptr, 0, nullptr, b_pool0, nullptr, (void*)m0, N0, F);
    }
    // 2) agg0 = segment_max(m0[esrc0], edst0)
    scatter_max_kernel<128><<<(E0 + 3) / 4, 256, 0, stream>>>(m0, esrc0, edst0, (int*)agg0, E0);

    // 3) h = relu(h_item[:N1] @ W_self0 + agg0 @ W_neigh0 + bias0)
    {
        dim3 g(N1 / TILE_BM, (2 * F) / TILE_BN);
        gemm_fused<true, true, false, false><<<g, 256, 0, stream>>>(
            h_item, F, W_self0, agg0, F, W_neigh0, bias0, nullptr, (void*)h, N1, 2 * F);
    }
    // 4) m1 = relu(h @ W_pool1 + b_pool1) -> bf16
    {
        dim3 g(N1 / TILE_BM, (2 * F) / TILE_BN);
        gemm_fused<false, true, true, false><<<g, 256, 0, stream>>>(
            h, 2 * F, W_pool1, nullptr, 0, nullptr, b_pool1, nullptr, (void*)m1, N1, 2 * F);
    }
    // 5) agg1 = segment_max(m1[esrc1], edst1)
    scatter_max_kernel<256><<<(E1 + 1) / 2, 256, 0, stream>>>(m1, esrc1, edst1, (int*)agg1, E1);

    // 6) out = h_item_dst + h[:N2] @ W_self1 + agg1 @ W_neigh1 + bias1
    {
        dim3 g(N2 / TILE_BM, F / TILE_BN);
        gemm_fused<true, false, false, true><<<g, 256, 0, stream>>>(
            h, 2 * F, W_self1, agg1, 2 * F, W_neigh1, bias1, h_item_dst, d_out, N2, F);
    }
}

// Round 2
// 529.247 us; speedup vs baseline: 1.3190x; 1.3190x over previous
//
#include <hip/hip_runtime.h>
#include <hip/hip_bf16.h>
#include <cstdint>

// ---------------------------------------------------------------------------
// SAGENet (2-layer SAGEConv 'pool' aggregator).
// R2: segment-max via counting-sort + gather (no wide atomics).
// Shapes (fixed): F=128, N0=409600, N1=40960, N2=4096, E0=409600, E1=40960.
// Pipeline:
//   m0 = relu(h_item @ W_pool0 + b_pool0)              [N0,128]  (bf16)
//   agg0 = segment_max(m0[esrc0], edst0, N1)           [N1,128]  (fp32)
//   h  = relu(h_item[:N1]@W_self0 + agg0@W_neigh0 + bias0)  [N1,256]
//   m1 = relu(h @ W_pool1 + b_pool1)                   [N1,256]  (bf16)
//   agg1 = segment_max(m1[esrc1], edst1, N2)           [N2,256]
//   out = h_item_dst + h[:N2]@W_self1 + agg1@W_neigh1 + bias1  [N2,128]
// segment_max of relu'd (>=0) values with 0 identity == jnp semantics
// (empty segment -> -inf -> where(isfinite)->0).
// ---------------------------------------------------------------------------

typedef unsigned int uint32;

__device__ __forceinline__ float bf_to_f(unsigned short u) {
    union { uint32 u; float f; } cv; cv.u = ((uint32)u) << 16; return cv.f;
}
__device__ __forceinline__ unsigned short f_to_bf(float f) {
    union { float f; uint32 u; } cv; cv.f = f;
    uint32 u = cv.u;
    uint32 r = (u + 0x7FFFu + ((u >> 16) & 1u)) >> 16;  // RNE
    return (unsigned short)r;
}

#define TILE_BM 64
#define TILE_BN 128
#define TILE_BK 32

// C[M,N] = act( A0@W0 (+ A1@W1) + bias (+ addsrc) ), optional bf16 output.
template<bool HAS_A1, bool RELU, bool BF16_OUT, bool HAS_ADD>
__global__ __launch_bounds__(256, 2) void gemm_fused(
    const float* __restrict__ A0, int K0, const float* __restrict__ W0,
    const float* __restrict__ A1, int K1, const float* __restrict__ W1,
    const float* __restrict__ bias, const float* __restrict__ addsrc,
    void* __restrict__ Cout, int M, int N)
{
    __shared__ float As[TILE_BK][TILE_BM + 4];
    __shared__ float Ws[TILE_BK][TILE_BN + 4];

    const int tid = threadIdx.x;
    const int tx = tid & 15;
    const int ty = tid >> 4;
    const int row0 = blockIdx.x * TILE_BM;
    const int col0 = blockIdx.y * TILE_BN;

    float acc[4][8];
    #pragma unroll
    for (int i = 0; i < 4; ++i)
        #pragma unroll
        for (int j = 0; j < 8; ++j) acc[i][j] = 0.f;

    auto run_seg = [&](const float* __restrict__ A, int K, const float* __restrict__ W) {
        for (int kk = 0; kk < K; kk += TILE_BK) {
            __syncthreads();
            #pragma unroll
            for (int s = 0; s < 2; ++s) {
                int idx = tid + s * 256;
                int r   = idx >> 3;
                int kq  = idx & 7;
                float4 v = *(const float4*)(A + (size_t)(row0 + r) * K + kk + kq * 4);
                As[kq * 4 + 0][r] = v.x;
                As[kq * 4 + 1][r] = v.y;
                As[kq * 4 + 2][r] = v.z;
                As[kq * 4 + 3][r] = v.w;
            }
            #pragma unroll
            for (int s = 0; s < 4; ++s) {
                int idx = tid + s * 256;
                int kr  = idx >> 5;
                int cq  = idx & 31;
                float4 v = *(const float4*)(W + (size_t)(kk + kr) * N + col0 + cq * 4);
                *(float4*)&Ws[kr][cq * 4] = v;
            }
            __syncthreads();
            #pragma unroll
            for (int k = 0; k < TILE_BK; ++k) {
                float4 av = *(const float4*)&As[k][ty * 4];
                float4 w0 = *(const float4*)&Ws[k][tx * 8];
                float4 w1 = *(const float4*)&Ws[k][tx * 8 + 4];
                float a[4] = {av.x, av.y, av.z, av.w};
                float w[8] = {w0.x, w0.y, w0.z, w0.w, w1.x, w1.y, w1.z, w1.w};
                #pragma unroll
                for (int i = 0; i < 4; ++i)
                    #pragma unroll
                    for (int j = 0; j < 8; ++j)
                        acc[i][j] = fmaf(a[i], w[j], acc[i][j]);
            }
        }
    };

    run_seg(A0, K0, W0);
    if (HAS_A1) run_seg(A1, K1, W1);

    #pragma unroll
    for (int i = 0; i < 4; ++i) {
        const int r = row0 + ty * 4 + i;
        const int cbase = col0 + tx * 8;
        float out[8];
        #pragma unroll
        for (int j = 0; j < 8; ++j) {
            float v = acc[i][j] + bias[cbase + j];
            if (HAS_ADD) v += addsrc[(size_t)r * N + cbase + j];
            if (RELU) v = fmaxf(v, 0.f);
            out[j] = v;
        }
        if (BF16_OUT) {
            unsigned short us[8];
            #pragma unroll
            for (int j = 0; j < 8; ++j) us[j] = f_to_bf(out[j]);
            *(uint4*)((unsigned short*)Cout + (size_t)r * N + cbase) = *(uint4*)us;
        } else {
            float* C = (float*)Cout;
            *(float4*)(C + (size_t)r * N + cbase)     = make_float4(out[0], out[1], out[2], out[3]);
            *(float4*)(C + (size_t)r * N + cbase + 4) = make_float4(out[4], out[5], out[6], out[7]);
        }
    }
}

// ---------------- segment-max machinery (counting sort + gather) -----------

__global__ __launch_bounds__(256) void count_kernel(
    const int* __restrict__ edst, int* __restrict__ cnt, int E)
{
    int e = blockIdx.x * 256 + threadIdx.x;
    if (e < E) atomicAdd(&cnt[edst[e]], 1);
}

__device__ __forceinline__ int wave_incl_scan(int v) {
    #pragma unroll
    for (int s = 1; s < 64; s <<= 1) {
        int t = __shfl_up(v, s, 64);
        if ((int)(threadIdx.x & 63) >= s) v += t;
    }
    return v;
}

// Single-block exclusive scan over n (<=65536 here); writes off[0..n] and cur[0..n-1].
__global__ __launch_bounds__(1024) void exscan_kernel(
    const int* __restrict__ cnt, int* __restrict__ off, int* __restrict__ cur, int n)
{
    __shared__ int wpart[16];
    __shared__ int s_carry, s_tot;
    const int tid = threadIdx.x, lane = tid & 63, wid = tid >> 6;
    if (tid == 0) s_carry = 0;
    __syncthreads();
    for (int base = 0; base < n; base += 1024) {
        int c = s_carry;
        int i = base + tid;
        int v = (i < n) ? cnt[i] : 0;
        int iv = wave_incl_scan(v);
        if (lane == 63) wpart[wid] = iv;
        __syncthreads();
        if (wid == 0) {
            int w = (lane < 16) ? wpart[lane] : 0;
            int ws_ = wave_incl_scan(w);
            if (lane < 16) wpart[lane] = ws_ - w;   // exclusive wave offsets
            if (lane == 15) s_tot = ws_;            // chunk total
        }
        __syncthreads();
        int excl = c + wpart[wid] + iv - v;
        if (i < n) { off[i] = excl; cur[i] = excl; }
        if (tid == 0) s_carry = c + s_tot;
        __syncthreads();
    }
    if (tid == 0) off[n] = s_carry;
}

__global__ __launch_bounds__(256) void fill_kernel(
    const int* __restrict__ esrc, const int* __restrict__ edst,
    int* __restrict__ cur, int* __restrict__ srcs, int E)
{
    int e = blockIdx.x * 256 + threadIdx.x;
    if (e >= E) return;
    int p = atomicAdd(&cur[edst[e]], 1);
    srcs[p] = esrc[e];
}

// One wave per dst row: max over its bucketed src rows. Writes every row
// (empty segment -> 0), so no pre-zeroing of agg needed.
template<int F>
__global__ __launch_bounds__(256) void gather_max_kernel(
    const unsigned short* __restrict__ m, const int* __restrict__ off,
    const int* __restrict__ srcs, float* __restrict__ agg, int ndst)
{
    constexpr int PER = F / 64;   // bf16 feats per lane (2 or 4)
    int gw = (blockIdx.x * 256 + threadIdx.x) >> 6;
    if (gw >= ndst) return;
    int lane = threadIdx.x & 63;
    int beg = off[gw], end = off[gw + 1];
    float mx[PER];
    #pragma unroll
    for (int j = 0; j < PER; ++j) mx[j] = 0.f;
    for (int t = beg; t < end; ++t) {
        int s = srcs[t];
        const unsigned short* row = m + (size_t)s * F + lane * PER;
        if (PER == 2) {
            ushort2 v = *(const ushort2*)row;
            mx[0] = fmaxf(mx[0], bf_to_f(v.x));
            mx[1] = fmaxf(mx[1], bf_to_f(v.y));
        } else {
            ushort4 v = *(const ushort4*)row;
            mx[0] = fmaxf(mx[0], bf_to_f(v.x));
            mx[1] = fmaxf(mx[1], bf_to_f(v.y));
            mx[2] = fmaxf(mx[2], bf_to_f(v.z));
            mx[3] = fmaxf(mx[3], bf_to_f(v.w));
        }
    }
    float* o = agg + (size_t)gw * F + lane * PER;
    if (PER == 2) *(float2*)o = make_float2(mx[0], mx[1]);
    else          *(float4*)o = make_float4(mx[0], mx[1], mx[2], mx[3]);
}

// ---------------------------------------------------------------------------

extern "C" void kernel_launch(void* const* d_in, const int* in_sizes, int n_in,
                              void* d_out, int out_size, void* d_ws, size_t ws_size,
                              hipStream_t stream)
{
    const float* h_item     = (const float*)d_in[0];
    const float* h_item_dst = (const float*)d_in[1];
    const int*   esrc0      = (const int*)d_in[2];
    const int*   edst0      = (const int*)d_in[3];
    const int*   esrc1      = (const int*)d_in[4];
    const int*   edst1      = (const int*)d_in[5];
    const float* W_pool0  = (const float*)d_in[7];
    const float* b_pool0  = (const float*)d_in[8];
    const float* W_self0  = (const float*)d_in[9];
    const float* W_neigh0 = (const float*)d_in[10];
    const float* bias0    = (const float*)d_in[11];
    const float* W_pool1  = (const float*)d_in[12];
    const float* b_pool1  = (const float*)d_in[13];
    const float* W_self1  = (const float*)d_in[14];
    const float* W_neigh1 = (const float*)d_in[15];
    const float* bias1    = (const float*)d_in[16];

    const int F  = 128;
    const int N0 = in_sizes[0] / F;     // 409600
    const int N2 = in_sizes[1] / F;     // 4096
    const int E0 = in_sizes[2];         // 409600
    const int E1 = in_sizes[4];         // 40960
    const int N1 = 40960;               // num_mid (fixed)

    auto aup = [](size_t x) { return (x + 255) & ~(size_t)255; };
    char* base = (char*)d_ws;

    // Region A (105 MB): m0 during layer 0; reused for m1/agg1/sort1 in layer 1.
    unsigned short* m0 = (unsigned short*)base;
    size_t m0_b = aup((size_t)N0 * F * 2);
    // Region B: agg0
    float* agg0 = (float*)(base + m0_b);
    size_t agg0_b = aup((size_t)N1 * F * 4);
    // Region C: h
    float* h = (float*)(base + m0_b + agg0_b);
    size_t h_b = aup((size_t)N1 * 2 * F * 4);
    // Region D: layer-0 sort buffers
    int* cnt0  = (int*)(base + m0_b + agg0_b + h_b);
    int* off0  = cnt0 + N1;
    int* cur0  = off0 + N1 + 1;
    int* srcs0 = cur0 + N1;                       // E0 ints

    // Region A reuse (layer 1): m1 (21 MB) + agg1 (4.2 MB) + sort1
    unsigned short* m1 = (unsigned short*)base;
    size_t m1_b = aup((size_t)N1 * 2 * F * 2);
    float* agg1 = (float*)(base + m1_b);
    size_t agg1_b = aup((size_t)N2 * 2 * F * 4);
    int* cnt1  = (int*)(base + m1_b + agg1_b);
    int* off1  = cnt1 + N2;
    int* cur1  = off1 + N2 + 1;
    int* srcs1 = cur1 + N2;                       // E1 ints

    // 1) m0 = relu(h_item @ W_pool0 + b_pool0) -> bf16
    {
        dim3 g(N0 / TILE_BM, F / TILE_BN);
        gemm_fused<false, true, true, false><<<g, 256, 0, stream>>>(
            h_item, F, W_pool0, nullptr, 0, nullptr, b_pool0, nullptr, (void*)m0, N0, F);
    }
    // 2) agg0 = segment_max(m0[esrc0], edst0)  [counting sort + gather]
    hipMemsetAsync(cnt0, 0, (size_t)N1 * 4, stream);
    count_kernel<<<(E0 + 255) / 256, 256, 0, stream>>>(edst0, cnt0, E0);
    exscan_kernel<<<1, 1024, 0, stream>>>(cnt0, off0, cur0, N1);
    fill_kernel<<<(E0 + 255) / 256, 256, 0, stream>>>(esrc0, edst0, cur0, srcs0, E0);
    gather_max_kernel<128><<<(N1 + 3) / 4, 256, 0, stream>>>(m0, off0, srcs0, agg0, N1);

    // 3) h = relu(h_item[:N1] @ W_self0 + agg0 @ W_neigh0 + bias0)
    {
        dim3 g(N1 / TILE_BM, (2 * F) / TILE_BN);
        gemm_fused<true, true, false, false><<<g, 256, 0, stream>>>(
            h_item, F, W_self0, agg0, F, W_neigh0, bias0, nullptr, (void*)h, N1, 2 * F);
    }
    // 4) m1 = relu(h @ W_pool1 + b_pool1) -> bf16   (overwrites m0 region; m0 dead)
    {
        dim3 g(N1 / TILE_BM, (2 * F) / TILE_BN);
        gemm_fused<false, true, true, false><<<g, 256, 0, stream>>>(
            h, 2 * F, W_pool1, nullptr, 0, nullptr, b_pool1, nullptr, (void*)m1, N1, 2 * F);
    }
    // 5) agg1 = segment_max(m1[esrc1], edst1)
    hipMemsetAsync(cnt1, 0, (size_t)N2 * 4, stream);
    count_kernel<<<(E1 + 255) / 256, 256, 0, stream>>>(edst1, cnt1, E1);
    exscan_kernel<<<1, 1024, 0, stream>>>(cnt1, off1, cur1, N2);
    fill_kernel<<<(E1 + 255) / 256, 256, 0, stream>>>(esrc1, edst1, cur1, srcs1, E1);
    gather_max_kernel<256><<<(N2 + 3) / 4, 256, 0, stream>>>(m1, off1, srcs1, agg1, N2);

    // 6) out = h_item_dst + h[:N2] @ W_self1 + agg1 @ W_neigh1 + bias1
    {
        dim3 g(N2 / TILE_BM, F / TILE_BN);
        gemm_fused<true, false, false, true><<<g, 256, 0, stream>>>(
            h, 2 * F, W_self1, agg1, 2 * F, W_neigh1, bias1, h_item_dst, d_out, N2, F);
    }
}

// Round 3
// 315.399 us; speedup vs baseline: 2.2134x; 1.6780x over previous
//
#include <hip/hip_runtime.h>
#include <hip/hip_bf16.h>
#include <cstdint>

// ---------------------------------------------------------------------------
// SAGENet (2-layer SAGEConv 'pool').
// R3: all GEMMs on bf16 MFMA (16x16x32), weights pre-packed to B-fragment
// layout, A staged fp32->bf16 into padded LDS. Segment-max stays
// counting-sort + gather.
// Shapes (fixed): F=128, N0=409600, N1=40960, N2=4096, E0=409600, E1=40960.
// ---------------------------------------------------------------------------

typedef unsigned int uint32;
typedef unsigned short ushort_t;

typedef __attribute__((ext_vector_type(8))) short short8v;   // 8 bf16 (4 VGPR)
typedef __attribute__((ext_vector_type(4))) float float4v;   // MFMA acc

__device__ __forceinline__ float bf_to_f(unsigned short u) {
    union { uint32 u; float f; } cv; cv.u = ((uint32)u) << 16; return cv.f;
}
__device__ __forceinline__ unsigned short f_to_bf(float f) {
    union { float f; uint32 u; } cv; cv.f = f;
    uint32 u = cv.u;
    uint32 r = (u + 0x7FFFu + ((u >> 16) & 1u)) >> 16;  // RNE
    return (unsigned short)r;
}

// ---------------- MFMA GEMM ------------------------------------------------
// Per-segment: stage A[128][KT] fp32 -> bf16 LDS, then MFMA-accumulate.
// LDS layout [128][KT+8] bf16: row stride (KT+8)*2 B is 16B-aligned and lands
// rows 4 banks apart -> ~2-way conflicts (free).
// Wp packed layout: [k/8][N][8] bf16 -> B-frag = 16B contiguous per lane.
template<int KT>
__device__ __forceinline__ void gemm_seg(
    const float* __restrict__ A, const ushort_t* __restrict__ Wp, int N,
    int row0, int col0, int tid, int wr, int wc, int l15, int g,
    ushort_t* lds, float4v (&acc)[4][4])
{
    constexpr int ldl = KT + 8;
    __syncthreads();   // protect LDS from previous segment's readers
    constexpr int C4 = KT / 4;             // float4s per row
    constexpr int TOT = 128 * C4;
    #pragma unroll 4
    for (int L = tid; L < TOT; L += 256) {
        int row = L / C4;                  // compile-time divisor
        int c4  = (L % C4) * 4;
        float4 v = *(const float4*)(A + (size_t)(row0 + row) * KT + c4);
        ushort4 pk = make_ushort4(f_to_bf(v.x), f_to_bf(v.y), f_to_bf(v.z), f_to_bf(v.w));
        *(ushort4*)&lds[row * ldl + c4] = pk;
    }
    __syncthreads();

    #pragma unroll
    for (int s = 0; s < KT / 32; ++s) {
        const int kb = s * 4 + g;          // k-block of 8 for this lane group
        short8v bfr[4], afr[4];
        #pragma unroll
        for (int ni = 0; ni < 4; ++ni) {
            int col = col0 + wc * 64 + ni * 16 + l15;
            bfr[ni] = *(const short8v*)(Wp + ((size_t)kb * N + col) * 8);
        }
        #pragma unroll
        for (int mi = 0; mi < 4; ++mi) {
            int row = wr * 64 + mi * 16 + l15;
            afr[mi] = *(const short8v*)&lds[row * ldl + s * 32 + g * 8];
        }
        #pragma unroll
        for (int mi = 0; mi < 4; ++mi)
            #pragma unroll
            for (int ni = 0; ni < 4; ++ni)
                acc[mi][ni] = __builtin_amdgcn_mfma_f32_16x16x32_bf16(
                    afr[mi], bfr[ni], acc[mi][ni], 0, 0, 0);
    }
}

// C[M,N] = act( A0@W0 (+ A1@W1) + bias (+ addsrc) ). 128x128 tile per block,
// 4 waves 2x2, wave tile 64x64 (4x4 fragments of 16x16).
template<bool RELU, bool BF16_OUT, bool HAS_ADD, int K0T, int K1T>
__global__ __launch_bounds__(256, 3) void gemm_mfma(
    const float* __restrict__ A0, const ushort_t* __restrict__ Wp0,
    const float* __restrict__ A1, const ushort_t* __restrict__ Wp1,
    const float* __restrict__ bias, const float* __restrict__ addsrc,
    void* __restrict__ Cout, int N)
{
    extern __shared__ ushort_t lds[];
    const int tid  = threadIdx.x;
    const int lane = tid & 63;
    const int wid  = tid >> 6;
    const int wr = wid >> 1, wc = wid & 1;
    const int row0 = blockIdx.x * 128;
    const int col0 = blockIdx.y * 128;
    const int l15 = lane & 15, g = lane >> 4;

    float4v acc[4][4];
    #pragma unroll
    for (int i = 0; i < 4; ++i)
        #pragma unroll
        for (int j = 0; j < 4; ++j)
            acc[i][j] = (float4v){0.f, 0.f, 0.f, 0.f};

    gemm_seg<K0T>(A0, Wp0, N, row0, col0, tid, wr, wc, l15, g, lds, acc);
    if constexpr (K1T > 0)
        gemm_seg<K1T>(A1, Wp1, N, row0, col0, tid, wr, wc, l15, g, lds, acc);

    // epilogue: C/D layout col=lane&15, row=(lane>>4)*4+reg  [m89-verified]
    #pragma unroll
    for (int mi = 0; mi < 4; ++mi) {
        #pragma unroll
        for (int ni = 0; ni < 4; ++ni) {
            const int rowb = row0 + wr * 64 + mi * 16 + g * 4;
            const int col  = col0 + wc * 64 + ni * 16 + l15;
            const float bs = bias[col];
            #pragma unroll
            for (int q = 0; q < 4; ++q) {
                float v = acc[mi][ni][q] + bs;
                if (HAS_ADD) v += addsrc[(size_t)(rowb + q) * N + col];
                if (RELU) v = fmaxf(v, 0.f);
                if (BF16_OUT) ((ushort_t*)Cout)[(size_t)(rowb + q) * N + col] = f_to_bf(v);
                else          ((float*)Cout)[(size_t)(rowb + q) * N + col] = v;
            }
        }
    }
}

// ---------------- weight packing ------------------------------------------
// fp32 W[K][N] -> bf16 packed [k/8][N][8]
struct PSeg { const float* src; ushort_t* dst; int lgN; int N; int base; };

__global__ __launch_bounds__(256) void pack_weights(
    PSeg s0, PSeg s1, PSeg s2, PSeg s3, PSeg s4, PSeg s5, int total)
{
    int idx = blockIdx.x * 256 + threadIdx.x;
    if (idx >= total) return;
    PSeg s;
    if      (idx >= s5.base) s = s5;
    else if (idx >= s4.base) s = s4;
    else if (idx >= s3.base) s = s3;
    else if (idx >= s2.base) s = s2;
    else if (idx >= s1.base) s = s1;
    else                     s = s0;
    int e = idx - s.base;
    int k = e >> s.lgN;
    int n = e & (s.N - 1);
    s.dst[((size_t)(k >> 3) * s.N + n) * 8 + (k & 7)] = f_to_bf(s.src[e]);
}

// ---------------- segment-max machinery (counting sort + gather) -----------

__global__ __launch_bounds__(256) void count_kernel(
    const int* __restrict__ edst, int* __restrict__ cnt, int E)
{
    int e = blockIdx.x * 256 + threadIdx.x;
    if (e < E) atomicAdd(&cnt[edst[e]], 1);
}

__device__ __forceinline__ int wave_incl_scan(int v) {
    #pragma unroll
    for (int s = 1; s < 64; s <<= 1) {
        int t = __shfl_up(v, s, 64);
        if ((int)(threadIdx.x & 63) >= s) v += t;
    }
    return v;
}

__global__ __launch_bounds__(1024) void exscan_kernel(
    const int* __restrict__ cnt, int* __restrict__ off, int* __restrict__ cur, int n)
{
    __shared__ int wpart[16];
    __shared__ int s_carry, s_tot;
    const int tid = threadIdx.x, lane = tid & 63, wid = tid >> 6;
    if (tid == 0) s_carry = 0;
    __syncthreads();
    for (int base = 0; base < n; base += 1024) {
        int c = s_carry;
        int i = base + tid;
        int v = (i < n) ? cnt[i] : 0;
        int iv = wave_incl_scan(v);
        if (lane == 63) wpart[wid] = iv;
        __syncthreads();
        if (wid == 0) {
            int w = (lane < 16) ? wpart[lane] : 0;
            int ws_ = wave_incl_scan(w);
            if (lane < 16) wpart[lane] = ws_ - w;
            if (lane == 15) s_tot = ws_;
        }
        __syncthreads();
        int excl = c + wpart[wid] + iv - v;
        if (i < n) { off[i] = excl; cur[i] = excl; }
        if (tid == 0) s_carry = c + s_tot;
        __syncthreads();
    }
    if (tid == 0) off[n] = s_carry;
}

__global__ __launch_bounds__(256) void fill_kernel(
    const int* __restrict__ esrc, const int* __restrict__ edst,
    int* __restrict__ cur, int* __restrict__ srcs, int E)
{
    int e = blockIdx.x * 256 + threadIdx.x;
    if (e >= E) return;
    int p = atomicAdd(&cur[edst[e]], 1);
    srcs[p] = esrc[e];
}

template<int F>
__global__ __launch_bounds__(256) void gather_max_kernel(
    const unsigned short* __restrict__ m, const int* __restrict__ off,
    const int* __restrict__ srcs, float* __restrict__ agg, int ndst)
{
    constexpr int PER = F / 64;
    int gw = (blockIdx.x * 256 + threadIdx.x) >> 6;
    if (gw >= ndst) return;
    int lane = threadIdx.x & 63;
    int beg = off[gw], end = off[gw + 1];
    float mx[PER];
    #pragma unroll
    for (int j = 0; j < PER; ++j) mx[j] = 0.f;
    for (int t = beg; t < end; ++t) {
        int s = srcs[t];
        const unsigned short* row = m + (size_t)s * F + lane * PER;
        if (PER == 2) {
            ushort2 v = *(const ushort2*)row;
            mx[0] = fmaxf(mx[0], bf_to_f(v.x));
            mx[1] = fmaxf(mx[1], bf_to_f(v.y));
        } else {
            ushort4 v = *(const ushort4*)row;
            mx[0] = fmaxf(mx[0], bf_to_f(v.x));
            mx[1] = fmaxf(mx[1], bf_to_f(v.y));
            mx[2] = fmaxf(mx[2], bf_to_f(v.z));
            mx[3] = fmaxf(mx[3], bf_to_f(v.w));
        }
    }
    float* o = agg + (size_t)gw * F + lane * PER;
    if (PER == 2) *(float2*)o = make_float2(mx[0], mx[1]);
    else          *(float4*)o = make_float4(mx[0], mx[1], mx[2], mx[3]);
}

// ---------------------------------------------------------------------------

extern "C" void kernel_launch(void* const* d_in, const int* in_sizes, int n_in,
                              void* d_out, int out_size, void* d_ws, size_t ws_size,
                              hipStream_t stream)
{
    const float* h_item     = (const float*)d_in[0];
    const float* h_item_dst = (const float*)d_in[1];
    const int*   esrc0      = (const int*)d_in[2];
    const int*   edst0      = (const int*)d_in[3];
    const int*   esrc1      = (const int*)d_in[4];
    const int*   edst1      = (const int*)d_in[5];
    const float* W_pool0  = (const float*)d_in[7];
    const float* b_pool0  = (const float*)d_in[8];
    const float* W_self0  = (const float*)d_in[9];
    const float* W_neigh0 = (const float*)d_in[10];
    const float* bias0    = (const float*)d_in[11];
    const float* W_pool1  = (const float*)d_in[12];
    const float* b_pool1  = (const float*)d_in[13];
    const float* W_self1  = (const float*)d_in[14];
    const float* W_neigh1 = (const float*)d_in[15];
    const float* bias1    = (const float*)d_in[16];

    const int F  = 128;
    const int N0 = in_sizes[0] / F;     // 409600
    const int N2 = in_sizes[1] / F;     // 4096
    const int E0 = in_sizes[2];         // 409600
    const int E1 = in_sizes[4];         // 40960
    const int N1 = 40960;               // num_mid (fixed)

    auto aup = [](size_t x) { return (x + 255) & ~(size_t)255; };
    char* base = (char*)d_ws;

    // Region A (105 MB): m0 in layer 0; reused for m1/agg1/sort1 in layer 1.
    unsigned short* m0 = (unsigned short*)base;
    size_t m0_b = aup((size_t)N0 * F * 2);
    float* agg0 = (float*)(base + m0_b);
    size_t agg0_b = aup((size_t)N1 * F * 4);
    float* h = (float*)(base + m0_b + agg0_b);
    size_t h_b = aup((size_t)N1 * 2 * F * 4);
    int* cnt0  = (int*)(base + m0_b + agg0_b + h_b);
    int* off0  = cnt0 + N1;
    int* cur0  = off0 + N1 + 1;
    int* srcs0 = cur0 + N1;                        // E0 ints
    size_t sort0_b = aup((size_t)(N1 * 3 + 1 + E0) * 4);

    // Packed weights (bf16), after sort0 region.
    ushort_t* wpk = (ushort_t*)(base + m0_b + agg0_b + h_b + sort0_b);
    ushort_t* p_pool0  = wpk;                       // 128x128
    ushort_t* p_self0  = p_pool0  + 128 * 128;      // 128x256
    ushort_t* p_neigh0 = p_self0  + 128 * 256;      // 128x256
    ushort_t* p_pool1  = p_neigh0 + 128 * 256;      // 256x256
    ushort_t* p_self1  = p_pool1  + 256 * 256;      // 256x128
    ushort_t* p_neigh1 = p_self1  + 256 * 128;      // 256x128

    // Layer-1 aliases over region A.
    unsigned short* m1 = (unsigned short*)base;
    size_t m1_b = aup((size_t)N1 * 2 * F * 2);
    float* agg1 = (float*)(base + m1_b);
    size_t agg1_b = aup((size_t)N2 * 2 * F * 4);
    int* cnt1  = (int*)(base + m1_b + agg1_b);
    int* off1  = cnt1 + N2;
    int* cur1  = off1 + N2 + 1;
    int* srcs1 = cur1 + N2;

    // 0) pack all weights to bf16 fragment layout
    {
        PSeg s0{W_pool0,  p_pool0,  7, 128, 0};
        PSeg s1{W_self0,  p_self0,  8, 256, 16384};
        PSeg s2{W_neigh0, p_neigh0, 8, 256, 16384 + 32768};
        PSeg s3{W_pool1,  p_pool1,  8, 256, 16384 + 65536};
        PSeg s4{W_self1,  p_self1,  7, 128, 16384 + 65536 + 65536};
        PSeg s5{W_neigh1, p_neigh1, 7, 128, 16384 + 65536 + 65536 + 32768};
        int total = 16384 + 65536 + 65536 + 65536 + 32768;  // 212992... (sum of all)
        total = 16384 + 32768 + 32768 + 65536 + 32768 + 32768;
        pack_weights<<<(total + 255) / 256, 256, 0, stream>>>(s0, s1, s2, s3, s4, s5, total);
    }

    const uint32 LDS128 = (128 + 8) * 128 * 2;   // 34816
    const uint32 LDS256 = (256 + 8) * 128 * 2;   // 67584

    // 1) m0 = relu(h_item @ W_pool0 + b_pool0) -> bf16
    {
        dim3 g(N0 / 128, F / 128);
        gemm_mfma<true, true, false, 128, 0><<<g, 256, LDS128, stream>>>(
            h_item, p_pool0, nullptr, nullptr, b_pool0, nullptr, (void*)m0, F);
    }
    // 2) agg0 = segment_max(m0[esrc0], edst0)
    hipMemsetAsync(cnt0, 0, (size_t)N1 * 4, stream);
    count_kernel<<<(E0 + 255) / 256, 256, 0, stream>>>(edst0, cnt0, E0);
    exscan_kernel<<<1, 1024, 0, stream>>>(cnt0, off0, cur0, N1);
    fill_kernel<<<(E0 + 255) / 256, 256, 0, stream>>>(esrc0, edst0, cur0, srcs0, E0);
    gather_max_kernel<128><<<(N1 + 3) / 4, 256, 0, stream>>>(m0, off0, srcs0, agg0, N1);

    // 3) h = relu(h_item[:N1]@W_self0 + agg0@W_neigh0 + bias0)   [N1,256]
    {
        dim3 g(N1 / 128, (2 * F) / 128);
        gemm_mfma<true, false, false, 128, 128><<<g, 256, LDS128, stream>>>(
            h_item, p_self0, agg0, p_neigh0, bias0, nullptr, (void*)h, 2 * F);
    }
    // 4) m1 = relu(h @ W_pool1 + b_pool1) -> bf16   [N1,256]
    {
        dim3 g(N1 / 128, (2 * F) / 128);
        gemm_mfma<true, true, false, 256, 0><<<g, 256, LDS256, stream>>>(
            h, p_pool1, nullptr, nullptr, b_pool1, nullptr, (void*)m1, 2 * F);
    }
    // 5) agg1 = segment_max(m1[esrc1], edst1)
    hipMemsetAsync(cnt1, 0, (size_t)N2 * 4, stream);
    count_kernel<<<(E1 + 255) / 256, 256, 0, stream>>>(edst1, cnt1, E1);
    exscan_kernel<<<1, 1024, 0, stream>>>(cnt1, off1, cur1, N2);
    fill_kernel<<<(E1 + 255) / 256, 256, 0, stream>>>(esrc1, edst1, cur1, srcs1, E1);
    gather_max_kernel<256><<<(N2 + 3) / 4, 256, 0, stream>>>(m1, off1, srcs1, agg1, N2);

    // 6) out = h_item_dst + h[:N2]@W_self1 + agg1@W_neigh1 + bias1   [N2,128]
    {
        dim3 g(N2 / 128, F / 128);
        gemm_mfma<false, false, true, 256, 256><<<g, 256, LDS256, stream>>>(
            h, p_self1, agg1, p_neigh1, bias1, h_item_dst, d_out, F);
    }
}

// Round 4
// 293.564 us; speedup vs baseline: 2.3780x; 1.0744x over previous
//
#include <hip/hip_runtime.h>
#include <hip/hip_bf16.h>
#include <cstdint>

// ---------------------------------------------------------------------------
// SAGENet (2-layer SAGEConv 'pool').
// R4: no hipMemsetAsync (counter zeroing fused into pack kernel), fast
// 3-phase single-block exscan, sort1 buffers un-aliased. GEMMs stay on
// bf16 MFMA 16x16x32 (verified R3).
// Shapes (fixed): F=128, N0=409600, N1=40960, N2=4096, E0=409600, E1=40960.
// ---------------------------------------------------------------------------

typedef unsigned int uint32;
typedef unsigned short ushort_t;

typedef __attribute__((ext_vector_type(8))) short short8v;   // 8 bf16 (4 VGPR)
typedef __attribute__((ext_vector_type(4))) float float4v;   // MFMA acc

__device__ __forceinline__ float bf_to_f(unsigned short u) {
    union { uint32 u; float f; } cv; cv.u = ((uint32)u) << 16; return cv.f;
}
__device__ __forceinline__ unsigned short f_to_bf(float f) {
    union { float f; uint32 u; } cv; cv.f = f;
    uint32 u = cv.u;
    uint32 r = (u + 0x7FFFu + ((u >> 16) & 1u)) >> 16;  // RNE
    return (unsigned short)r;
}

// ---------------- MFMA GEMM ------------------------------------------------
// Per-segment: stage A[128][KT] fp32 -> bf16 LDS, then MFMA-accumulate.
// LDS layout [128][KT+8] bf16 (rows 4 banks apart -> ~2-way conflicts, free).
// Wp packed layout: [k/8][N][8] bf16 -> B-frag = 16B contiguous per lane.
template<int KT>
__device__ __forceinline__ void gemm_seg(
    const float* __restrict__ A, const ushort_t* __restrict__ Wp, int N,
    int row0, int col0, int tid, int wr, int wc, int l15, int g,
    ushort_t* lds, float4v (&acc)[4][4])
{
    constexpr int ldl = KT + 8;
    __syncthreads();   // protect LDS from previous segment's readers
    constexpr int C4 = KT / 4;             // float4s per row
    constexpr int TOT = 128 * C4;
    #pragma unroll 4
    for (int L = tid; L < TOT; L += 256) {
        int row = L / C4;
        int c4  = (L % C4) * 4;
        float4 v = *(const float4*)(A + (size_t)(row0 + row) * KT + c4);
        ushort4 pk = make_ushort4(f_to_bf(v.x), f_to_bf(v.y), f_to_bf(v.z), f_to_bf(v.w));
        *(ushort4*)&lds[row * ldl + c4] = pk;
    }
    __syncthreads();

    #pragma unroll
    for (int s = 0; s < KT / 32; ++s) {
        const int kb = s * 4 + g;
        short8v bfr[4], afr[4];
        #pragma unroll
        for (int ni = 0; ni < 4; ++ni) {
            int col = col0 + wc * 64 + ni * 16 + l15;
            bfr[ni] = *(const short8v*)(Wp + ((size_t)kb * N + col) * 8);
        }
        #pragma unroll
        for (int mi = 0; mi < 4; ++mi) {
            int row = wr * 64 + mi * 16 + l15;
            afr[mi] = *(const short8v*)&lds[row * ldl + s * 32 + g * 8];
        }
        #pragma unroll
        for (int mi = 0; mi < 4; ++mi)
            #pragma unroll
            for (int ni = 0; ni < 4; ++ni)
                acc[mi][ni] = __builtin_amdgcn_mfma_f32_16x16x32_bf16(
                    afr[mi], bfr[ni], acc[mi][ni], 0, 0, 0);
    }
}

template<bool RELU, bool BF16_OUT, bool HAS_ADD, int K0T, int K1T>
__global__ __launch_bounds__(256, 3) void gemm_mfma(
    const float* __restrict__ A0, const ushort_t* __restrict__ Wp0,
    const float* __restrict__ A1, const ushort_t* __restrict__ Wp1,
    const float* __restrict__ bias, const float* __restrict__ addsrc,
    void* __restrict__ Cout, int N)
{
    extern __shared__ ushort_t lds[];
    const int tid  = threadIdx.x;
    const int lane = tid & 63;
    const int wid  = tid >> 6;
    const int wr = wid >> 1, wc = wid & 1;
    const int row0 = blockIdx.x * 128;
    const int col0 = blockIdx.y * 128;
    const int l15 = lane & 15, g = lane >> 4;

    float4v acc[4][4];
    #pragma unroll
    for (int i = 0; i < 4; ++i)
        #pragma unroll
        for (int j = 0; j < 4; ++j)
            acc[i][j] = (float4v){0.f, 0.f, 0.f, 0.f};

    gemm_seg<K0T>(A0, Wp0, N, row0, col0, tid, wr, wc, l15, g, lds, acc);
    if constexpr (K1T > 0)
        gemm_seg<K1T>(A1, Wp1, N, row0, col0, tid, wr, wc, l15, g, lds, acc);

    // epilogue: C/D layout col=lane&15, row=(lane>>4)*4+reg  [m89-verified]
    #pragma unroll
    for (int mi = 0; mi < 4; ++mi) {
        #pragma unroll
        for (int ni = 0; ni < 4; ++ni) {
            const int rowb = row0 + wr * 64 + mi * 16 + g * 4;
            const int col  = col0 + wc * 64 + ni * 16 + l15;
            const float bs = bias[col];
            #pragma unroll
            for (int q = 0; q < 4; ++q) {
                float v = acc[mi][ni][q] + bs;
                if (HAS_ADD) v += addsrc[(size_t)(rowb + q) * N + col];
                if (RELU) v = fmaxf(v, 0.f);
                if (BF16_OUT) ((ushort_t*)Cout)[(size_t)(rowb + q) * N + col] = f_to_bf(v);
                else          ((float*)Cout)[(size_t)(rowb + q) * N + col] = v;
            }
        }
    }
}

// ---------------- weight packing + counter zeroing -------------------------
// fp32 W[K][N] -> bf16 packed [k/8][N][8]; also zeroes cnt0/cnt1 (graph-safe
// replacement for hipMemsetAsync, which showed ~120us dispatch cost).
struct PSeg { const float* src; ushort_t* dst; int lgN; int N; int base; };

__global__ __launch_bounds__(256) void pack_weights(
    PSeg s0, PSeg s1, PSeg s2, PSeg s3, PSeg s4, PSeg s5, int total,
    int* __restrict__ cnt0, int n0, int* __restrict__ cnt1, int n1)
{
    int idx = blockIdx.x * 256 + threadIdx.x;
    if (idx < n0) cnt0[idx] = 0;
    if (idx < n1) cnt1[idx] = 0;
    if (idx >= total) return;
    PSeg s;
    if      (idx >= s5.base) s = s5;
    else if (idx >= s4.base) s = s4;
    else if (idx >= s3.base) s = s3;
    else if (idx >= s2.base) s = s2;
    else if (idx >= s1.base) s = s1;
    else                     s = s0;
    int e = idx - s.base;
    int k = e >> s.lgN;
    int n = e & (s.N - 1);
    s.dst[((size_t)(k >> 3) * s.N + n) * 8 + (k & 7)] = f_to_bf(s.src[e]);
}

// ---------------- segment-max machinery (counting sort + gather) -----------

__global__ __launch_bounds__(256) void count_kernel(
    const int* __restrict__ edst, int* __restrict__ cnt, int E)
{
    int e = blockIdx.x * 256 + threadIdx.x;
    if (e < E) atomicAdd(&cnt[edst[e]], 1);
}

__device__ __forceinline__ int wave_incl_scan(int v) {
    #pragma unroll
    for (int s = 1; s < 64; s <<= 1) {
        int t = __shfl_up(v, s, 64);
        if ((int)(threadIdx.x & 63) >= s) v += t;
    }
    return v;
}

// 3-phase single-block exclusive scan: n == 1024*C exactly.
// Phase 1: per-thread chunk sum. Phase 2: 1024-wide scan of sums.
// Phase 3: per-thread prefix write. Writes off[0..n] and cur[0..n-1].
template<int C>
__global__ __launch_bounds__(1024) void exscan_kernel(
    const int* __restrict__ cnt, int* __restrict__ off, int* __restrict__ cur, int n)
{
    __shared__ int wsum[16];
    const int tid = threadIdx.x, lane = tid & 63, wid = tid >> 6;
    const int base = tid * C;
    int s = 0;
    #pragma unroll 4
    for (int i = 0; i < C; ++i) s += cnt[base + i];
    int is = wave_incl_scan(s);
    if (lane == 63) wsum[wid] = is;
    __syncthreads();
    if (wid == 0) {
        int w = (lane < 16) ? wsum[lane] : 0;
        int ws_ = wave_incl_scan(w);
        if (lane < 16) wsum[lane] = ws_ - w;   // exclusive wave offsets
    }
    __syncthreads();
    int excl = wsum[wid] + is - s;
    #pragma unroll 4
    for (int i = 0; i < C; ++i) {
        int c = cnt[base + i];
        off[base + i] = excl;
        cur[base + i] = excl;
        excl += c;
    }
    if (tid == 1023) off[n] = excl;
}

__global__ __launch_bounds__(256) void fill_kernel(
    const int* __restrict__ esrc, const int* __restrict__ edst,
    int* __restrict__ cur, int* __restrict__ srcs, int E)
{
    int e = blockIdx.x * 256 + threadIdx.x;
    if (e >= E) return;
    int p = atomicAdd(&cur[edst[e]], 1);
    srcs[p] = esrc[e];
}

template<int F>
__global__ __launch_bounds__(256) void gather_max_kernel(
    const unsigned short* __restrict__ m, const int* __restrict__ off,
    const int* __restrict__ srcs, float* __restrict__ agg, int ndst)
{
    constexpr int PER = F / 64;
    int gw = (blockIdx.x * 256 + threadIdx.x) >> 6;
    if (gw >= ndst) return;
    int lane = threadIdx.x & 63;
    int beg = off[gw], end = off[gw + 1];
    float mx[PER];
    #pragma unroll
    for (int j = 0; j < PER; ++j) mx[j] = 0.f;
    for (int t = beg; t < end; ++t) {
        int s = srcs[t];
        const unsigned short* row = m + (size_t)s * F + lane * PER;
        if (PER == 2) {
            ushort2 v = *(const ushort2*)row;
            mx[0] = fmaxf(mx[0], bf_to_f(v.x));
            mx[1] = fmaxf(mx[1], bf_to_f(v.y));
        } else {
            ushort4 v = *(const ushort4*)row;
            mx[0] = fmaxf(mx[0], bf_to_f(v.x));
            mx[1] = fmaxf(mx[1], bf_to_f(v.y));
            mx[2] = fmaxf(mx[2], bf_to_f(v.z));
            mx[3] = fmaxf(mx[3], bf_to_f(v.w));
        }
    }
    float* o = agg + (size_t)gw * F + lane * PER;
    if (PER == 2) *(float2*)o = make_float2(mx[0], mx[1]);
    else          *(float4*)o = make_float4(mx[0], mx[1], mx[2], mx[3]);
}

// ---------------------------------------------------------------------------

extern "C" void kernel_launch(void* const* d_in, const int* in_sizes, int n_in,
                              void* d_out, int out_size, void* d_ws, size_t ws_size,
                              hipStream_t stream)
{
    const float* h_item     = (const float*)d_in[0];
    const float* h_item_dst = (const float*)d_in[1];
    const int*   esrc0      = (const int*)d_in[2];
    const int*   edst0      = (const int*)d_in[3];
    const int*   esrc1      = (const int*)d_in[4];
    const int*   edst1      = (const int*)d_in[5];
    const float* W_pool0  = (const float*)d_in[7];
    const float* b_pool0  = (const float*)d_in[8];
    const float* W_self0  = (const float*)d_in[9];
    const float* W_neigh0 = (const float*)d_in[10];
    const float* bias0    = (const float*)d_in[11];
    const float* W_pool1  = (const float*)d_in[12];
    const float* b_pool1  = (const float*)d_in[13];
    const float* W_self1  = (const float*)d_in[14];
    const float* W_neigh1 = (const float*)d_in[15];
    const float* bias1    = (const float*)d_in[16];

    const int F  = 128;
    const int N0 = in_sizes[0] / F;     // 409600
    const int N2 = in_sizes[1] / F;     // 4096
    const int E0 = in_sizes[2];         // 409600
    const int E1 = in_sizes[4];         // 40960
    const int N1 = 40960;               // num_mid (fixed)

    auto aup = [](size_t x) { return (x + 255) & ~(size_t)255; };
    char* base = (char*)d_ws;

    // Region A (105 MB): m0 in layer 0; reused for m1/agg1 in layer 1.
    unsigned short* m0 = (unsigned short*)base;
    size_t m0_b = aup((size_t)N0 * F * 2);
    float* agg0 = (float*)(base + m0_b);
    size_t agg0_b = aup((size_t)N1 * F * 4);
    float* h = (float*)(base + m0_b + agg0_b);
    size_t h_b = aup((size_t)N1 * 2 * F * 4);
    // layer-0 sort buffers
    int* cnt0  = (int*)(base + m0_b + agg0_b + h_b);
    int* off0  = cnt0 + N1;
    int* cur0  = off0 + N1 + 1;
    int* srcs0 = cur0 + N1;                        // E0 ints
    size_t sort0_b = aup((size_t)(N1 * 3 + 1 + E0) * 4);

    // Packed weights (bf16)
    ushort_t* wpk = (ushort_t*)(base + m0_b + agg0_b + h_b + sort0_b);
    ushort_t* p_pool0  = wpk;                       // 128x128
    ushort_t* p_self0  = p_pool0  + 128 * 128;      // 128x256
    ushort_t* p_neigh0 = p_self0  + 128 * 256;      // 128x256
    ushort_t* p_pool1  = p_neigh0 + 128 * 256;      // 256x256
    ushort_t* p_self1  = p_pool1  + 256 * 256;      // 256x128
    ushort_t* p_neigh1 = p_self1  + 256 * 128;      // 256x128
    size_t wpk_b = aup((size_t)(16384 + 32768 + 32768 + 65536 + 32768 + 32768) * 2);

    // layer-1 sort buffers: in tail (NOT aliased with region A), so both
    // counter arrays can be zeroed by the first dispatch.
    int* cnt1  = (int*)((char*)wpk + wpk_b);
    int* off1  = cnt1 + N2;
    int* cur1  = off1 + N2 + 1;
    int* srcs1 = cur1 + N2;                        // E1 ints

    // Layer-1 aliases over region A (m0 dead by then).
    unsigned short* m1 = (unsigned short*)base;
    size_t m1_b = aup((size_t)N1 * 2 * F * 2);
    float* agg1 = (float*)(base + m1_b);

    // 0) pack weights + zero cnt0/cnt1
    {
        PSeg s0{W_pool0,  p_pool0,  7, 128, 0};
        PSeg s1{W_self0,  p_self0,  8, 256, 16384};
        PSeg s2{W_neigh0, p_neigh0, 8, 256, 49152};
        PSeg s3{W_pool1,  p_pool1,  8, 256, 81920};
        PSeg s4{W_self1,  p_self1,  7, 128, 147456};
        PSeg s5{W_neigh1, p_neigh1, 7, 128, 180224};
        const int total = 212992;
        pack_weights<<<(total + 255) / 256, 256, 0, stream>>>(
            s0, s1, s2, s3, s4, s5, total, cnt0, N1, cnt1, N2);
    }

    const uint32 LDS128 = (128 + 8) * 128 * 2;   // 34816
    const uint32 LDS256 = (256 + 8) * 128 * 2;   // 67584

    // 1) m0 = relu(h_item @ W_pool0 + b_pool0) -> bf16
    {
        dim3 g(N0 / 128, F / 128);
        gemm_mfma<true, true, false, 128, 0><<<g, 256, LDS128, stream>>>(
            h_item, p_pool0, nullptr, nullptr, b_pool0, nullptr, (void*)m0, F);
    }
    // 2) agg0 = segment_max(m0[esrc0], edst0)
    count_kernel<<<(E0 + 255) / 256, 256, 0, stream>>>(edst0, cnt0, E0);
    exscan_kernel<40><<<1, 1024, 0, stream>>>(cnt0, off0, cur0, N1);
    fill_kernel<<<(E0 + 255) / 256, 256, 0, stream>>>(esrc0, edst0, cur0, srcs0, E0);
    gather_max_kernel<128><<<(N1 + 3) / 4, 256, 0, stream>>>(m0, off0, srcs0, agg0, N1);

    // 3) h = relu(h_item[:N1]@W_self0 + agg0@W_neigh0 + bias0)   [N1,256]
    {
        dim3 g(N1 / 128, (2 * F) / 128);
        gemm_mfma<true, false, false, 128, 128><<<g, 256, LDS128, stream>>>(
            h_item, p_self0, agg0, p_neigh0, bias0, nullptr, (void*)h, 2 * F);
    }
    // 4) m1 = relu(h @ W_pool1 + b_pool1) -> bf16   [N1,256]
    {
        dim3 g(N1 / 128, (2 * F) / 128);
        gemm_mfma<true, true, false, 256, 0><<<g, 256, LDS256, stream>>>(
            h, p_pool1, nullptr, nullptr, b_pool1, nullptr, (void*)m1, 2 * F);
    }
    // 5) agg1 = segment_max(m1[esrc1], edst1)
    count_kernel<<<(E1 + 255) / 256, 256, 0, stream>>>(edst1, cnt1, E1);
    exscan_kernel<4><<<1, 1024, 0, stream>>>(cnt1, off1, cur1, N2);
    fill_kernel<<<(E1 + 255) / 256, 256, 0, stream>>>(esrc1, edst1, cur1, srcs1, E1);
    gather_max_kernel<256><<<(N2 + 3) / 4, 256, 0, stream>>>(m1, off1, srcs1, agg1, N2);

    // 6) out = h_item_dst + h[:N2]@W_self1 + agg1@W_neigh1 + bias1   [N2,128]
    {
        dim3 g(N2 / 128, F / 128);
        gemm_mfma<false, false, true, 256, 256><<<g, 256, LDS256, stream>>>(
            h, p_self1, agg1, p_neigh1, bias1, h_item_dst, d_out, F);
    }
}

// Round 5
// 266.560 us; speedup vs baseline: 2.6189x; 1.1013x over previous
//
#include <hip/hip_runtime.h>
#include <hip/hip_bf16.h>
#include <cstdint>

// ---------------------------------------------------------------------------
// SAGENet (2-layer SAGEConv 'pool').
// R5: (1) LDS-staged coalesced bf16 epilogue (was 64 scalar 2B stores/thread),
//     (2) h/agg0/agg1 stored bf16 (bit-identical: staging rounded them anyway),
//     (3) sort pipeline consolidated (13 -> 10 dispatches).
// GEMMs on bf16 MFMA 16x16x32, weights pre-packed [k/8][N][8] (verified R3/R4).
// Shapes (fixed): F=128, N0=409600, N1=40960, N2=4096, E0=409600, E1=40960.
// ---------------------------------------------------------------------------

typedef unsigned int uint32;
typedef unsigned short ushort_t;

typedef __attribute__((ext_vector_type(8))) short short8v;   // 8 bf16 (4 VGPR)
typedef __attribute__((ext_vector_type(4))) float float4v;   // MFMA acc

__device__ __forceinline__ float bf_to_f(unsigned short u) {
    union { uint32 u; float f; } cv; cv.u = ((uint32)u) << 16; return cv.f;
}
__device__ __forceinline__ unsigned short f_to_bf(float f) {
    union { float f; uint32 u; } cv; cv.f = f;
    uint32 u = cv.u;
    uint32 r = (u + 0x7FFFu + ((u >> 16) & 1u)) >> 16;  // RNE
    return (unsigned short)r;
}

// ---------------- MFMA GEMM ------------------------------------------------
// Stage A[128][KT] (fp32->bf16 cvt, or bf16 copy) into LDS [128][KT+8];
// row stride (KT+8)*2B == 4-bank shift/row -> ~2-way conflicts (free).
// Wp packed [k/8][N][8] bf16 -> B-frag is one 16B load per lane.
template<int KT, bool ABF>
__device__ __forceinline__ void gemm_seg(
    const void* __restrict__ Av, const ushort_t* __restrict__ Wp, int N,
    int row0, int col0, int tid, int wr, int wc, int l15, int g,
    ushort_t* lds, float4v (&acc)[4][4])
{
    constexpr int ldl = KT + 8;
    __syncthreads();   // protect LDS from previous phase's readers
    if constexpr (ABF) {
        const ushort_t* A = (const ushort_t*)Av;
        constexpr int C8 = KT / 8;
        constexpr int TOT = 128 * C8;
        #pragma unroll 4
        for (int L = tid; L < TOT; L += 256) {
            int row = L / C8;
            int c8  = (L % C8) * 8;
            *(uint4*)&lds[row * ldl + c8] =
                *(const uint4*)((const ushort_t*)A + (size_t)(row0 + row) * KT + c8);
        }
    } else {
        const float* A = (const float*)Av;
        constexpr int C4 = KT / 4;
        constexpr int TOT = 128 * C4;
        #pragma unroll 4
        for (int L = tid; L < TOT; L += 256) {
            int row = L / C4;
            int c4  = (L % C4) * 4;
            float4 v = *(const float4*)(A + (size_t)(row0 + row) * KT + c4);
            ushort4 pk = make_ushort4(f_to_bf(v.x), f_to_bf(v.y), f_to_bf(v.z), f_to_bf(v.w));
            *(ushort4*)&lds[row * ldl + c4] = pk;
        }
    }
    __syncthreads();

    #pragma unroll
    for (int s = 0; s < KT / 32; ++s) {
        const int kb = s * 4 + g;
        short8v bfr[4], afr[4];
        #pragma unroll
        for (int ni = 0; ni < 4; ++ni) {
            int col = col0 + wc * 64 + ni * 16 + l15;
            bfr[ni] = *(const short8v*)(Wp + ((size_t)kb * N + col) * 8);
        }
        #pragma unroll
        for (int mi = 0; mi < 4; ++mi) {
            int row = wr * 64 + mi * 16 + l15;
            afr[mi] = *(const short8v*)&lds[row * ldl + s * 32 + g * 8];
        }
        #pragma unroll
        for (int mi = 0; mi < 4; ++mi)
            #pragma unroll
            for (int ni = 0; ni < 4; ++ni)
                acc[mi][ni] = __builtin_amdgcn_mfma_f32_16x16x32_bf16(
                    afr[mi], bfr[ni], acc[mi][ni], 0, 0, 0);
    }
}

// 128x128 tile/block, 4 waves 2x2, wave tile 64x64 (4x4 frags of 16x16x32).
template<bool RELU, bool BF16_OUT, bool HAS_ADD, int K0T, int K1T, bool A0BF, bool A1BF, int MINW>
__global__ __launch_bounds__(256, MINW) void gemm_mfma(
    const void* __restrict__ A0, const ushort_t* __restrict__ Wp0,
    const void* __restrict__ A1, const ushort_t* __restrict__ Wp1,
    const float* __restrict__ bias, const float* __restrict__ addsrc,
    void* __restrict__ Cout, int N)
{
    extern __shared__ ushort_t lds[];
    const int tid  = threadIdx.x;
    const int lane = tid & 63;
    const int wid  = tid >> 6;
    const int wr = wid >> 1, wc = wid & 1;
    const int row0 = blockIdx.x * 128;
    const int col0 = blockIdx.y * 128;
    const int l15 = lane & 15, g = lane >> 4;

    float4v acc[4][4];
    #pragma unroll
    for (int i = 0; i < 4; ++i)
        #pragma unroll
        for (int j = 0; j < 4; ++j)
            acc[i][j] = (float4v){0.f, 0.f, 0.f, 0.f};

    gemm_seg<K0T, A0BF>(A0, Wp0, N, row0, col0, tid, wr, wc, l15, g, lds, acc);
    if constexpr (K1T > 0)
        gemm_seg<K1T, A1BF>(A1, Wp1, N, row0, col0, tid, wr, wc, l15, g, lds, acc);

    // epilogue: C/D layout col=lane&15, row=(lane>>4)*4+reg  [m89-verified]
    if constexpr (BF16_OUT) {
        // stage bf16 tile in LDS [128][136] (4-bank row shift), then coalesced
        // 16B stores: 8 uint4 per thread.
        __syncthreads();   // all MFMA LDS reads done before overwrite
        #pragma unroll
        for (int mi = 0; mi < 4; ++mi) {
            #pragma unroll
            for (int ni = 0; ni < 4; ++ni) {
                const int rowl = wr * 64 + mi * 16 + g * 4;
                const int coll = wc * 64 + ni * 16 + l15;
                const float bs = bias[col0 + coll];
                #pragma unroll
                for (int q = 0; q < 4; ++q) {
                    float v = acc[mi][ni][q] + bs;
                    if (RELU) v = fmaxf(v, 0.f);
                    lds[(rowl + q) * 136 + coll] = f_to_bf(v);
                }
            }
        }
        __syncthreads();
        ushort_t* Cb = (ushort_t*)Cout;
        const int rloc = tid >> 4, c8 = (tid & 15) * 8;
        #pragma unroll
        for (int p = 0; p < 8; ++p) {
            int r = p * 16 + rloc;
            uint4 v = *(const uint4*)&lds[r * 136 + c8];
            *(uint4*)&Cb[(size_t)(row0 + r) * N + col0 + c8] = v;
        }
    } else {
        float* C = (float*)Cout;
        #pragma unroll
        for (int mi = 0; mi < 4; ++mi) {
            #pragma unroll
            for (int ni = 0; ni < 4; ++ni) {
                const int rowb = row0 + wr * 64 + mi * 16 + g * 4;
                const int col  = col0 + wc * 64 + ni * 16 + l15;
                const float bs = bias[col];
                #pragma unroll
                for (int q = 0; q < 4; ++q) {
                    float v = acc[mi][ni][q] + bs;
                    if (HAS_ADD) v += addsrc[(size_t)(rowb + q) * N + col];
                    if (RELU) v = fmaxf(v, 0.f);
                    C[(size_t)(rowb + q) * N + col] = v;
                }
            }
        }
    }
}

// ---------------- weight packing + counter zeroing -------------------------
struct PSeg { const float* src; ushort_t* dst; int lgN; int N; int base; };

__global__ __launch_bounds__(256) void pack_weights(
    PSeg s0, PSeg s1, PSeg s2, PSeg s3, PSeg s4, PSeg s5, int total,
    int* __restrict__ cnt0, int n0, int* __restrict__ cnt1, int n1)
{
    int idx = blockIdx.x * 256 + threadIdx.x;
    if (idx < n0) cnt0[idx] = 0;
    if (idx < n1) cnt1[idx] = 0;
    if (idx >= total) return;
    PSeg s;
    if      (idx >= s5.base) s = s5;
    else if (idx >= s4.base) s = s4;
    else if (idx >= s3.base) s = s3;
    else if (idx >= s2.base) s = s2;
    else if (idx >= s1.base) s = s1;
    else                     s = s0;
    int e = idx - s.base;
    int k = e >> s.lgN;
    int n = e & (s.N - 1);
    s.dst[((size_t)(k >> 3) * s.N + n) * 8 + (k & 7)] = f_to_bf(s.src[e]);
}

// ---------------- segment-max machinery (counting sort + gather) -----------

// counts for BOTH layers in one dispatch (edge lists are data-independent).
__global__ __launch_bounds__(256) void count2_kernel(
    const int* __restrict__ edst0, int* __restrict__ cnt0, int E0,
    const int* __restrict__ edst1, int* __restrict__ cnt1, int E1)
{
    int e = blockIdx.x * 256 + threadIdx.x;
    if (e < E0) atomicAdd(&cnt0[edst0[e]], 1);
    int e1 = e - E0;
    if (e1 >= 0 && e1 < E1) atomicAdd(&cnt1[edst1[e1]], 1);
}

__device__ __forceinline__ int wave_incl_scan(int v) {
    #pragma unroll
    for (int s = 1; s < 64; s <<= 1) {
        int t = __shfl_up(v, s, 64);
        if ((int)(threadIdx.x & 63) >= s) v += t;
    }
    return v;
}

// per-block 3-phase exclusive scan over n == 1024*C.
template<int C>
__device__ __forceinline__ void exscan_impl(
    const int* __restrict__ cnt, int* __restrict__ off, int* __restrict__ cur,
    int n, int* wsum)
{
    const int tid = threadIdx.x, lane = tid & 63, wid = tid >> 6;
    const int base = tid * C;
    int s = 0;
    #pragma unroll 4
    for (int i = 0; i < C; ++i) s += cnt[base + i];
    int is = wave_incl_scan(s);
    if (lane == 63) wsum[wid] = is;
    __syncthreads();
    if (wid == 0) {
        int w = (lane < 16) ? wsum[lane] : 0;
        int ws_ = wave_incl_scan(w);
        if (lane < 16) wsum[lane] = ws_ - w;
    }
    __syncthreads();
    int excl = wsum[wid] + is - s;
    #pragma unroll 4
    for (int i = 0; i < C; ++i) {
        int c = cnt[base + i];
        off[base + i] = excl;
        cur[base + i] = excl;
        excl += c;
    }
    if (tid == 1023) off[n] = excl;
}

__global__ __launch_bounds__(1024) void exscan2_kernel(
    const int* __restrict__ cnt0, int* __restrict__ off0, int* __restrict__ cur0, int n0,
    const int* __restrict__ cnt1, int* __restrict__ off1, int* __restrict__ cur1, int n1)
{
    __shared__ int wsum[16];
    if (blockIdx.x == 0) exscan_impl<40>(cnt0, off0, cur0, n0, wsum);
    else                 exscan_impl<4>(cnt1, off1, cur1, n1, wsum);
}

__global__ __launch_bounds__(256) void fill2_kernel(
    const int* __restrict__ esrc0, const int* __restrict__ edst0,
    int* __restrict__ cur0, int* __restrict__ srcs0, int E0,
    const int* __restrict__ esrc1, const int* __restrict__ edst1,
    int* __restrict__ cur1, int* __restrict__ srcs1, int E1)
{
    int e = blockIdx.x * 256 + threadIdx.x;
    if (e < E0) {
        int p = atomicAdd(&cur0[edst0[e]], 1);
        srcs0[p] = esrc0[e];
    }
    int e1 = e - E0;
    if (e1 >= 0 && e1 < E1) {
        int p = atomicAdd(&cur1[edst1[e1]], 1);
        srcs1[p] = esrc1[e1];
    }
}

// One wave per dst row; integer max on non-negative bf16 bit patterns
// (order-isomorphic to float for >=0). Writes every row (empty -> 0).
template<int F>
__global__ __launch_bounds__(256) void gather_max_kernel(
    const ushort_t* __restrict__ m, const int* __restrict__ off,
    const int* __restrict__ srcs, ushort_t* __restrict__ agg, int ndst)
{
    constexpr int PER = F / 64;   // 2 or 4
    int gw = (blockIdx.x * 256 + threadIdx.x) >> 6;
    if (gw >= ndst) return;
    int lane = threadIdx.x & 63;
    int beg = off[gw], end = off[gw + 1];
    ushort_t mx[PER];
    #pragma unroll
    for (int j = 0; j < PER; ++j) mx[j] = 0;
    for (int t = beg; t < end; ++t) {
        int s = srcs[t];
        const ushort_t* row = m + (size_t)s * F + lane * PER;
        if (PER == 2) {
            ushort2 v = *(const ushort2*)row;
            mx[0] = mx[0] > v.x ? mx[0] : v.x;
            mx[1] = mx[1] > v.y ? mx[1] : v.y;
        } else {
            ushort4 v = *(const ushort4*)row;
            mx[0] = mx[0] > v.x ? mx[0] : v.x;
            mx[1] = mx[1] > v.y ? mx[1] : v.y;
            mx[2] = mx[2] > v.z ? mx[2] : v.z;
            mx[3] = mx[3] > v.w ? mx[3] : v.w;
        }
    }
    ushort_t* o = agg + (size_t)gw * F + lane * PER;
    if (PER == 2) *(ushort2*)o = make_ushort2(mx[0], mx[1]);
    else          *(ushort4*)o = make_ushort4(mx[0], mx[1], mx[2], mx[3]);
}

// ---------------------------------------------------------------------------

extern "C" void kernel_launch(void* const* d_in, const int* in_sizes, int n_in,
                              void* d_out, int out_size, void* d_ws, size_t ws_size,
                              hipStream_t stream)
{
    const float* h_item     = (const float*)d_in[0];
    const float* h_item_dst = (const float*)d_in[1];
    const int*   esrc0      = (const int*)d_in[2];
    const int*   edst0      = (const int*)d_in[3];
    const int*   esrc1      = (const int*)d_in[4];
    const int*   edst1      = (const int*)d_in[5];
    const float* W_pool0  = (const float*)d_in[7];
    const float* b_pool0  = (const float*)d_in[8];
    const float* W_self0  = (const float*)d_in[9];
    const float* W_neigh0 = (const float*)d_in[10];
    const float* bias0    = (const float*)d_in[11];
    const float* W_pool1  = (const float*)d_in[12];
    const float* b_pool1  = (const float*)d_in[13];
    const float* W_self1  = (const float*)d_in[14];
    const float* W_neigh1 = (const float*)d_in[15];
    const float* bias1    = (const float*)d_in[16];

    const int F  = 128;
    const int N0 = in_sizes[0] / F;     // 409600
    const int N2 = in_sizes[1] / F;     // 4096
    const int E0 = in_sizes[2];         // 409600
    const int E1 = in_sizes[4];         // 40960
    const int N1 = 40960;               // num_mid (fixed)

    auto aup = [](size_t x) { return (x + 255) & ~(size_t)255; };
    char* base = (char*)d_ws;

    // Region A (105 MB): m0 in layer 0; reused for m1/agg1 in layer 1.
    ushort_t* m0 = (ushort_t*)base;
    size_t m0_b = aup((size_t)N0 * F * 2);
    ushort_t* agg0 = (ushort_t*)(base + m0_b);               // bf16 [N1,128]
    size_t agg0_b = aup((size_t)N1 * F * 2);
    ushort_t* h = (ushort_t*)(base + m0_b + agg0_b);         // bf16 [N1,256]
    size_t h_b = aup((size_t)N1 * 2 * F * 2);
    // layer-0 sort buffers
    int* cnt0  = (int*)(base + m0_b + agg0_b + h_b);
    int* off0  = cnt0 + N1;
    int* cur0  = off0 + N1 + 1;
    int* srcs0 = cur0 + N1;                                  // E0 ints
    size_t sort0_b = aup((size_t)(N1 * 3 + 1 + E0) * 4);

    // Packed weights (bf16)
    ushort_t* wpk = (ushort_t*)(base + m0_b + agg0_b + h_b + sort0_b);
    ushort_t* p_pool0  = wpk;                       // 128x128
    ushort_t* p_self0  = p_pool0  + 128 * 128;      // 128x256
    ushort_t* p_neigh0 = p_self0  + 128 * 256;      // 128x256
    ushort_t* p_pool1  = p_neigh0 + 128 * 256;      // 256x256
    ushort_t* p_self1  = p_pool1  + 256 * 256;      // 256x128
    ushort_t* p_neigh1 = p_self1  + 256 * 128;      // 256x128
    size_t wpk_b = aup((size_t)212992 * 2);

    // layer-1 sort buffers (tail; NOT aliased, zeroed up-front)
    int* cnt1  = (int*)((char*)wpk + wpk_b);
    int* off1  = cnt1 + N2;
    int* cur1  = off1 + N2 + 1;
    int* srcs1 = cur1 + N2;                                  // E1 ints

    // Layer-1 aliases over region A (m0 dead by then).
    ushort_t* m1 = (ushort_t*)base;                          // bf16 [N1,256]
    size_t m1_b = aup((size_t)N1 * 2 * F * 2);
    ushort_t* agg1 = (ushort_t*)(base + m1_b);               // bf16 [N2,256]

    // 0) pack weights + zero cnt0/cnt1
    {
        PSeg s0{W_pool0,  p_pool0,  7, 128, 0};
        PSeg s1{W_self0,  p_self0,  8, 256, 16384};
        PSeg s2{W_neigh0, p_neigh0, 8, 256, 49152};
        PSeg s3{W_pool1,  p_pool1,  8, 256, 81920};
        PSeg s4{W_self1,  p_self1,  7, 128, 147456};
        PSeg s5{W_neigh1, p_neigh1, 7, 128, 180224};
        const int total = 212992;
        pack_weights<<<(total + 255) / 256, 256, 0, stream>>>(
            s0, s1, s2, s3, s4, s5, total, cnt0, N1, cnt1, N2);
    }
    // sort structure (data-independent of features): count -> scan -> fill
    count2_kernel<<<(E0 + E1 + 255) / 256, 256, 0, stream>>>(
        edst0, cnt0, E0, edst1, cnt1, E1);
    exscan2_kernel<<<2, 1024, 0, stream>>>(cnt0, off0, cur0, N1, cnt1, off1, cur1, N2);
    fill2_kernel<<<(E0 + E1 + 255) / 256, 256, 0, stream>>>(
        esrc0, edst0, cur0, srcs0, E0, esrc1, edst1, cur1, srcs1, E1);

    const uint32 LDS128 = (128 + 8) * 128 * 2;   // 34816 (also 128x136 out tile)
    const uint32 LDS256 = (256 + 8) * 128 * 2;   // 67584

    // 1) m0 = relu(h_item @ W_pool0 + b_pool0) -> bf16
    {
        dim3 g(N0 / 128, F / 128);
        gemm_mfma<true, true, false, 128, 0, false, false, 4><<<g, 256, LDS128, stream>>>(
            h_item, p_pool0, nullptr, nullptr, b_pool0, nullptr, (void*)m0, F);
    }
    // 2) agg0 = segment_max(m0[esrc0], edst0) -> bf16
    gather_max_kernel<128><<<(N1 + 3) / 4, 256, 0, stream>>>(m0, off0, srcs0, agg0, N1);

    // 3) h = relu(h_item[:N1]@W_self0 + agg0@W_neigh0 + bias0) -> bf16 [N1,256]
    {
        dim3 g(N1 / 128, (2 * F) / 128);
        gemm_mfma<true, true, false, 128, 128, false, true, 4><<<g, 256, LDS128, stream>>>(
            h_item, p_self0, agg0, p_neigh0, bias0, nullptr, (void*)h, 2 * F);
    }
    // 4) m1 = relu(h @ W_pool1 + b_pool1) -> bf16 [N1,256]
    {
        dim3 g(N1 / 128, (2 * F) / 128);
        gemm_mfma<true, true, false, 256, 0, true, false, 2><<<g, 256, LDS256, stream>>>(
            h, p_pool1, nullptr, nullptr, b_pool1, nullptr, (void*)m1, 2 * F);
    }
    // 5) agg1 = segment_max(m1[esrc1], edst1) -> bf16
    gather_max_kernel<256><<<(N2 + 3) / 4, 256, 0, stream>>>(m1, off1, srcs1, agg1, N2);

    // 6) out = h_item_dst + h[:N2]@W_self1 + agg1@W_neigh1 + bias1   [N2,128] fp32
    {
        dim3 g(N2 / 128, F / 128);
        gemm_mfma<false, false, true, 256, 256, true, true, 2><<<g, 256, LDS256, stream>>>(
            h, p_self1, agg1, p_neigh1, bias1, h_item_dst, d_out, F);
    }
}

// Round 6
// 212.776 us; speedup vs baseline: 3.2809x; 1.2528x over previous
//
#include <hip/hip_runtime.h>
#include <hip/hip_bf16.h>
#include <cstdint>

// ---------------------------------------------------------------------------
// SAGENet (2-layer SAGEConv 'pool').
// R6: layer-0 pool GEMM + segment-max FUSED over dst-sorted edges (m0 never
// materialized; saves 210 MB round-trip). Interior segments: plain stores;
// block-boundary segments: int-punned fp32 atomicMax (values >= 0).
// GEMMs on bf16 MFMA 16x16x32, weights pre-packed [k/8][N][8] (verified R3-R5).
// Shapes (fixed): F=128, N0=409600, N1=40960, N2=4096, E0=409600, E1=40960.
// E0 % 128 == 0 (3200 blocks exactly).
// ---------------------------------------------------------------------------

typedef unsigned int uint32;
typedef unsigned short ushort_t;

typedef __attribute__((ext_vector_type(8))) short short8v;   // 8 bf16 (4 VGPR)
typedef __attribute__((ext_vector_type(4))) float float4v;   // MFMA acc

__device__ __forceinline__ float bf_to_f(unsigned short u) {
    union { uint32 u; float f; } cv; cv.u = ((uint32)u) << 16; return cv.f;
}
__device__ __forceinline__ unsigned short f_to_bf(float f) {
    union { float f; uint32 u; } cv; cv.f = f;
    uint32 u = cv.u;
    uint32 r = (u + 0x7FFFu + ((u >> 16) & 1u)) >> 16;  // RNE
    return (unsigned short)r;
}

__device__ __forceinline__ int wave_incl_scan(int v) {
    #pragma unroll
    for (int s = 1; s < 64; s <<= 1) {
        int t = __shfl_up(v, s, 64);
        if ((int)(threadIdx.x & 63) >= s) v += t;
    }
    return v;
}

// ---------------- MFMA GEMM ------------------------------------------------
template<int KT, bool ABF>
__device__ __forceinline__ void gemm_seg(
    const void* __restrict__ Av, const ushort_t* __restrict__ Wp, int N,
    int row0, int col0, int tid, int wr, int wc, int l15, int g,
    ushort_t* lds, float4v (&acc)[4][4])
{
    constexpr int ldl = KT + 8;
    __syncthreads();
    if constexpr (ABF) {
        const ushort_t* A = (const ushort_t*)Av;
        constexpr int C8 = KT / 8;
        constexpr int TOT = 128 * C8;
        #pragma unroll 4
        for (int L = tid; L < TOT; L += 256) {
            int row = L / C8;
            int c8  = (L % C8) * 8;
            *(uint4*)&lds[row * ldl + c8] =
                *(const uint4*)(A + (size_t)(row0 + row) * KT + c8);
        }
    } else {
        const float* A = (const float*)Av;
        constexpr int C4 = KT / 4;
        constexpr int TOT = 128 * C4;
        #pragma unroll 4
        for (int L = tid; L < TOT; L += 256) {
            int row = L / C4;
            int c4  = (L % C4) * 4;
            float4 v = *(const float4*)(A + (size_t)(row0 + row) * KT + c4);
            ushort4 pk = make_ushort4(f_to_bf(v.x), f_to_bf(v.y), f_to_bf(v.z), f_to_bf(v.w));
            *(ushort4*)&lds[row * ldl + c4] = pk;
        }
    }
    __syncthreads();

    #pragma unroll
    for (int s = 0; s < KT / 32; ++s) {
        const int kb = s * 4 + g;
        short8v bfr[4], afr[4];
        #pragma unroll
        for (int ni = 0; ni < 4; ++ni) {
            int col = col0 + wc * 64 + ni * 16 + l15;
            bfr[ni] = *(const short8v*)(Wp + ((size_t)kb * N + col) * 8);
        }
        #pragma unroll
        for (int mi = 0; mi < 4; ++mi) {
            int row = wr * 64 + mi * 16 + l15;
            afr[mi] = *(const short8v*)&lds[row * ldl + s * 32 + g * 8];
        }
        #pragma unroll
        for (int mi = 0; mi < 4; ++mi)
            #pragma unroll
            for (int ni = 0; ni < 4; ++ni)
                acc[mi][ni] = __builtin_amdgcn_mfma_f32_16x16x32_bf16(
                    afr[mi], bfr[ni], acc[mi][ni], 0, 0, 0);
    }
}

template<bool RELU, bool BF16_OUT, bool HAS_ADD, int K0T, int K1T, bool A0BF, bool A1BF, int MINW>
__global__ __launch_bounds__(256, MINW) void gemm_mfma(
    const void* __restrict__ A0, const ushort_t* __restrict__ Wp0,
    const void* __restrict__ A1, const ushort_t* __restrict__ Wp1,
    const float* __restrict__ bias, const float* __restrict__ addsrc,
    void* __restrict__ Cout, int N)
{
    extern __shared__ ushort_t lds[];
    const int tid  = threadIdx.x;
    const int lane = tid & 63;
    const int wid  = tid >> 6;
    const int wr = wid >> 1, wc = wid & 1;
    const int row0 = blockIdx.x * 128;
    const int col0 = blockIdx.y * 128;
    const int l15 = lane & 15, g = lane >> 4;

    float4v acc[4][4];
    #pragma unroll
    for (int i = 0; i < 4; ++i)
        #pragma unroll
        for (int j = 0; j < 4; ++j)
            acc[i][j] = (float4v){0.f, 0.f, 0.f, 0.f};

    gemm_seg<K0T, A0BF>(A0, Wp0, N, row0, col0, tid, wr, wc, l15, g, lds, acc);
    if constexpr (K1T > 0)
        gemm_seg<K1T, A1BF>(A1, Wp1, N, row0, col0, tid, wr, wc, l15, g, lds, acc);

    // epilogue: C/D layout col=lane&15, row=(lane>>4)*4+reg  [m89-verified]
    if constexpr (BF16_OUT) {
        __syncthreads();
        #pragma unroll
        for (int mi = 0; mi < 4; ++mi) {
            #pragma unroll
            for (int ni = 0; ni < 4; ++ni) {
                const int rowl = wr * 64 + mi * 16 + g * 4;
                const int coll = wc * 64 + ni * 16 + l15;
                const float bs = bias[col0 + coll];
                #pragma unroll
                for (int q = 0; q < 4; ++q) {
                    float v = acc[mi][ni][q] + bs;
                    if (RELU) v = fmaxf(v, 0.f);
                    lds[(rowl + q) * 136 + coll] = f_to_bf(v);
                }
            }
        }
        __syncthreads();
        ushort_t* Cb = (ushort_t*)Cout;
        const int rloc = tid >> 4, c8 = (tid & 15) * 8;
        #pragma unroll
        for (int p = 0; p < 8; ++p) {
            int r = p * 16 + rloc;
            uint4 v = *(const uint4*)&lds[r * 136 + c8];
            *(uint4*)&Cb[(size_t)(row0 + r) * N + col0 + c8] = v;
        }
    } else {
        float* C = (float*)Cout;
        #pragma unroll
        for (int mi = 0; mi < 4; ++mi) {
            #pragma unroll
            for (int ni = 0; ni < 4; ++ni) {
                const int rowb = row0 + wr * 64 + mi * 16 + g * 4;
                const int col  = col0 + wc * 64 + ni * 16 + l15;
                const float bs = bias[col];
                #pragma unroll
                for (int q = 0; q < 4; ++q) {
                    float v = acc[mi][ni][q] + bs;
                    if (HAS_ADD) v += addsrc[(size_t)(rowb + q) * N + col];
                    if (RELU) v = fmaxf(v, 0.f);
                    C[(size_t)(rowb + q) * N + col] = v;
                }
            }
        }
    }
}

// ---------------- fused layer-0 pool GEMM + segment-max --------------------
// Block b: 128 dst-sorted edges [r0, r0+128). Gathers h_item rows via srcs,
// computes relu(A@Wpool0 + b) tile in LDS (bf16), then per-segment max.
// Interior segments -> plain float2 stores; boundary segments -> atomicMax
// (int-punned fp32, values >= 0; agg pre-zeroed).
__global__ __launch_bounds__(256, 4) void pool0_fused(
    const float* __restrict__ hsrc, const ushort_t* __restrict__ Wp,
    const float* __restrict__ bias,
    const int* __restrict__ srcs, const int* __restrict__ dsts,
    int* __restrict__ agg, int E)
{
    constexpr int KT = 128, ldl = KT + 8;      // 136
    extern __shared__ ushort_t lds[];          // [128][136] staged A, then T
    __shared__ int sIdx[128], sd[128];
    __shared__ int segbeg[129];
    __shared__ int wps[4];
    __shared__ int s_first_start, s_last_end;

    const int tid  = threadIdx.x;
    const int lane = tid & 63;
    const int wid  = tid >> 6;
    const int wr = wid >> 1, wc = wid & 1;
    const int l15 = lane & 15, g = lane >> 4;
    const int r0 = blockIdx.x * 128;

    if (tid < 128) { sIdx[tid] = srcs[r0 + tid]; sd[tid] = dsts[r0 + tid]; }
    __syncthreads();

    // stage gathered A rows (fp32 -> bf16)
    #pragma unroll 4
    for (int L = tid; L < 128 * 32; L += 256) {
        int row = L >> 5;
        int c4  = (L & 31) * 4;
        float4 v = *(const float4*)(hsrc + (size_t)sIdx[row] * KT + c4);
        ushort4 pk = make_ushort4(f_to_bf(v.x), f_to_bf(v.y), f_to_bf(v.z), f_to_bf(v.w));
        *(ushort4*)&lds[row * ldl + c4] = pk;
    }
    __syncthreads();

    float4v acc[4][4];
    #pragma unroll
    for (int i = 0; i < 4; ++i)
        #pragma unroll
        for (int j = 0; j < 4; ++j)
            acc[i][j] = (float4v){0.f, 0.f, 0.f, 0.f};

    #pragma unroll
    for (int s = 0; s < KT / 32; ++s) {
        const int kb = s * 4 + g;
        short8v bfr[4], afr[4];
        #pragma unroll
        for (int ni = 0; ni < 4; ++ni) {
            int col = wc * 64 + ni * 16 + l15;
            bfr[ni] = *(const short8v*)(Wp + ((size_t)kb * 128 + col) * 8);
        }
        #pragma unroll
        for (int mi = 0; mi < 4; ++mi) {
            int row = wr * 64 + mi * 16 + l15;
            afr[mi] = *(const short8v*)&lds[row * ldl + s * 32 + g * 8];
        }
        #pragma unroll
        for (int mi = 0; mi < 4; ++mi)
            #pragma unroll
            for (int ni = 0; ni < 4; ++ni)
                acc[mi][ni] = __builtin_amdgcn_mfma_f32_16x16x32_bf16(
                    afr[mi], bfr[ni], acc[mi][ni], 0, 0, 0);
    }

    // write relu(acc + bias) as bf16 into T (reuse lds; stride 136)
    __syncthreads();
    #pragma unroll
    for (int mi = 0; mi < 4; ++mi) {
        #pragma unroll
        for (int ni = 0; ni < 4; ++ni) {
            const int rowl = wr * 64 + mi * 16 + g * 4;
            const int coll = wc * 64 + ni * 16 + l15;
            const float bs = bias[coll];
            #pragma unroll
            for (int q = 0; q < 4; ++q) {
                float v = fmaxf(acc[mi][ni][q] + bs, 0.f);
                lds[(rowl + q) * ldl + coll] = f_to_bf(v);
            }
        }
    }

    // segment metadata (dsts sorted -> non-decreasing within block)
    int flag = 0;
    if (tid < 128) flag = (tid == 0) || (sd[tid] != sd[tid - 1]);
    int isc = wave_incl_scan(flag);
    if (lane == 63) wps[wid] = isc;
    if (tid == 0) {
        s_first_start = (r0 == 0) || (dsts[r0 - 1] != sd[0]);
        s_last_end    = (r0 + 128 == E) || (dsts[r0 + 128] != sd[127]);
    }
    __syncthreads();
    int woff = (wid >= 1) ? wps[0] : 0;   // only waves 0/1 hold rows
    if (tid < 128 && flag) segbeg[woff + isc - 1] = tid;
    __syncthreads();
    const int nseg = wps[0] + wps[1];
    const bool first_start = s_first_start, last_end = s_last_end;

    // per-(segment, col-pair) max; 64 col-pairs cover 128 cols
    for (int it = tid; it < nseg * 64; it += 256) {
        int s  = it >> 6;
        int cp = it & 63;
        int beg = segbeg[s];
        int end = (s + 1 < nseg) ? segbeg[s + 1] : 128;
        int d = sd[beg];
        uint32 mx0 = 0, mx1 = 0;    // bf16 bits; unsigned order == float order for >=0
        for (int r = beg; r < end; ++r) {
            ushort2 v = *(const ushort2*)&lds[r * ldl + cp * 2];
            if (v.x > mx0) mx0 = v.x;
            if (v.y > mx1) mx1 = v.y;
        }
        float f0 = bf_to_f((ushort_t)mx0), f1 = bf_to_f((ushort_t)mx1);
        int* p = agg + (size_t)d * 128 + cp * 2;
        bool interior = (s > 0 || first_start) && (s < nseg - 1 || last_end);
        if (interior) {
            *(float2*)p = make_float2(f0, f1);
        } else {
            atomicMax(p,     __float_as_int(f0));
            atomicMax(p + 1, __float_as_int(f1));
        }
    }
}

// ---------------- weight packing + zero-init -------------------------------
struct PSeg { const float* src; ushort_t* dst; int lgN; int N; int base; };

__global__ __launch_bounds__(256) void pack_weights(
    PSeg s0, PSeg s1, PSeg s2, PSeg s3, PSeg s4, PSeg s5, int total,
    int* __restrict__ cnt0, int n0, int* __restrict__ cnt1, int n1,
    float4* __restrict__ aggz, int nz4)
{
    int idx = blockIdx.x * 256 + threadIdx.x;
    int nth = gridDim.x * 256;
    if (idx < n0) cnt0[idx] = 0;
    if (idx < n1) cnt1[idx] = 0;
    for (int i = idx; i < nz4; i += nth)
        aggz[i] = make_float4(0.f, 0.f, 0.f, 0.f);
    if (idx >= total) return;
    PSeg s;
    if      (idx >= s5.base) s = s5;
    else if (idx >= s4.base) s = s4;
    else if (idx >= s3.base) s = s3;
    else if (idx >= s2.base) s = s2;
    else if (idx >= s1.base) s = s1;
    else                     s = s0;
    int e = idx - s.base;
    int k = e >> s.lgN;
    int n = e & (s.N - 1);
    s.dst[((size_t)(k >> 3) * s.N + n) * 8 + (k & 7)] = f_to_bf(s.src[e]);
}

// ---------------- segment sort machinery -----------------------------------

__global__ __launch_bounds__(256) void count2_kernel(
    const int* __restrict__ edst0, int* __restrict__ cnt0, int E0,
    const int* __restrict__ edst1, int* __restrict__ cnt1, int E1)
{
    int e = blockIdx.x * 256 + threadIdx.x;
    if (e < E0) atomicAdd(&cnt0[edst0[e]], 1);
    int e1 = e - E0;
    if (e1 >= 0 && e1 < E1) atomicAdd(&cnt1[edst1[e1]], 1);
}

template<int C>
__device__ __forceinline__ void exscan_impl(
    const int* __restrict__ cnt, int* __restrict__ off, int* __restrict__ cur,
    int n, int* wsum)
{
    const int tid = threadIdx.x, lane = tid & 63, wid = tid >> 6;
    const int base = tid * C;
    int s = 0;
    #pragma unroll 4
    for (int i = 0; i < C; ++i) s += cnt[base + i];
    int is = wave_incl_scan(s);
    if (lane == 63) wsum[wid] = is;
    __syncthreads();
    if (wid == 0) {
        int w = (lane < 16) ? wsum[lane] : 0;
        int ws_ = wave_incl_scan(w);
        if (lane < 16) wsum[lane] = ws_ - w;
    }
    __syncthreads();
    int excl = wsum[wid] + is - s;
    #pragma unroll 4
    for (int i = 0; i < C; ++i) {
        int c = cnt[base + i];
        off[base + i] = excl;
        cur[base + i] = excl;
        excl += c;
    }
    if (tid == 1023) off[n] = excl;
}

__global__ __launch_bounds__(1024) void exscan2_kernel(
    const int* __restrict__ cnt0, int* __restrict__ off0, int* __restrict__ cur0, int n0,
    const int* __restrict__ cnt1, int* __restrict__ off1, int* __restrict__ cur1, int n1)
{
    __shared__ int wsum[16];
    if (blockIdx.x == 0) exscan_impl<40>(cnt0, off0, cur0, n0, wsum);
    else                 exscan_impl<4>(cnt1, off1, cur1, n1, wsum);
}

// fill: layer 0 writes srcs AND dsts (sorted); layer 1 only srcs.
__global__ __launch_bounds__(256) void fill2_kernel(
    const int* __restrict__ esrc0, const int* __restrict__ edst0,
    int* __restrict__ cur0, int* __restrict__ srcs0, int* __restrict__ dsts0, int E0,
    const int* __restrict__ esrc1, const int* __restrict__ edst1,
    int* __restrict__ cur1, int* __restrict__ srcs1, int E1)
{
    int e = blockIdx.x * 256 + threadIdx.x;
    if (e < E0) {
        int d = edst0[e];
        int p = atomicAdd(&cur0[d], 1);
        srcs0[p] = esrc0[e];
        dsts0[p] = d;
    }
    int e1 = e - E0;
    if (e1 >= 0 && e1 < E1) {
        int p = atomicAdd(&cur1[edst1[e1]], 1);
        srcs1[p] = esrc1[e1];
    }
}

// layer-1 gather-max (bf16 in/out), one wave per dst row.
template<int F>
__global__ __launch_bounds__(256) void gather_max_kernel(
    const ushort_t* __restrict__ m, const int* __restrict__ off,
    const int* __restrict__ srcs, ushort_t* __restrict__ agg, int ndst)
{
    constexpr int PER = F / 64;
    int gw = (blockIdx.x * 256 + threadIdx.x) >> 6;
    if (gw >= ndst) return;
    int lane = threadIdx.x & 63;
    int beg = off[gw], end = off[gw + 1];
    ushort_t mx[PER];
    #pragma unroll
    for (int j = 0; j < PER; ++j) mx[j] = 0;
    for (int t = beg; t < end; ++t) {
        int s = srcs[t];
        const ushort_t* row = m + (size_t)s * F + lane * PER;
        ushort4 v = *(const ushort4*)row;
        mx[0] = mx[0] > v.x ? mx[0] : v.x;
        mx[1] = mx[1] > v.y ? mx[1] : v.y;
        mx[2] = mx[2] > v.z ? mx[2] : v.z;
        mx[3] = mx[3] > v.w ? mx[3] : v.w;
    }
    ushort_t* o = agg + (size_t)gw * F + lane * PER;
    *(ushort4*)o = make_ushort4(mx[0], mx[1], mx[2], mx[3]);
}

// ---------------------------------------------------------------------------

extern "C" void kernel_launch(void* const* d_in, const int* in_sizes, int n_in,
                              void* d_out, int out_size, void* d_ws, size_t ws_size,
                              hipStream_t stream)
{
    const float* h_item     = (const float*)d_in[0];
    const float* h_item_dst = (const float*)d_in[1];
    const int*   esrc0      = (const int*)d_in[2];
    const int*   edst0      = (const int*)d_in[3];
    const int*   esrc1      = (const int*)d_in[4];
    const int*   edst1      = (const int*)d_in[5];
    const float* W_pool0  = (const float*)d_in[7];
    const float* b_pool0  = (const float*)d_in[8];
    const float* W_self0  = (const float*)d_in[9];
    const float* W_neigh0 = (const float*)d_in[10];
    const float* bias0    = (const float*)d_in[11];
    const float* W_pool1  = (const float*)d_in[12];
    const float* b_pool1  = (const float*)d_in[13];
    const float* W_self1  = (const float*)d_in[14];
    const float* W_neigh1 = (const float*)d_in[15];
    const float* bias1    = (const float*)d_in[16];

    const int F  = 128;
    const int N0 = in_sizes[0] / F;     // 409600
    const int N2 = in_sizes[1] / F;     // 4096
    const int E0 = in_sizes[2];         // 409600 (divisible by 128)
    const int E1 = in_sizes[4];         // 40960
    const int N1 = 40960;               // num_mid (fixed)

    auto aup = [](size_t x) { return (x + 255) & ~(size_t)255; };
    char* p = (char*)d_ws;

    float* agg0 = (float*)p;           p += aup((size_t)N1 * F * 4);       // fp32 [N1,128]
    ushort_t* h = (ushort_t*)p;        p += aup((size_t)N1 * 2 * F * 2);   // bf16 [N1,256]
    ushort_t* m1 = (ushort_t*)p;       p += aup((size_t)N1 * 2 * F * 2);   // bf16 [N1,256]
    ushort_t* agg1 = (ushort_t*)p;     p += aup((size_t)N2 * 2 * F * 2);   // bf16 [N2,256]
    int* cnt0  = (int*)p;              p += aup((size_t)N1 * 4);
    int* off0  = (int*)p;              p += aup((size_t)(N1 + 1) * 4);
    int* cur0  = (int*)p;              p += aup((size_t)N1 * 4);
    int* srcs0 = (int*)p;              p += aup((size_t)E0 * 4);
    int* dsts0 = (int*)p;              p += aup((size_t)E0 * 4);
    int* cnt1  = (int*)p;              p += aup((size_t)N2 * 4);
    int* off1  = (int*)p;              p += aup((size_t)(N2 + 1) * 4);
    int* cur1  = (int*)p;              p += aup((size_t)N2 * 4);
    int* srcs1 = (int*)p;              p += aup((size_t)E1 * 4);
    ushort_t* wpk = (ushort_t*)p;      p += aup((size_t)212992 * 2);
    ushort_t* p_pool0  = wpk;                       // 128x128
    ushort_t* p_self0  = p_pool0  + 128 * 128;      // 128x256
    ushort_t* p_neigh0 = p_self0  + 128 * 256;      // 128x256
    ushort_t* p_pool1  = p_neigh0 + 128 * 256;      // 256x256
    ushort_t* p_self1  = p_pool1  + 256 * 256;      // 256x128
    ushort_t* p_neigh1 = p_self1  + 256 * 128;      // 256x128

    // 0) pack weights + zero cnt0/cnt1/agg0
    {
        PSeg s0{W_pool0,  p_pool0,  7, 128, 0};
        PSeg s1{W_self0,  p_self0,  8, 256, 16384};
        PSeg s2{W_neigh0, p_neigh0, 8, 256, 49152};
        PSeg s3{W_pool1,  p_pool1,  8, 256, 81920};
        PSeg s4{W_self1,  p_self1,  7, 128, 147456};
        PSeg s5{W_neigh1, p_neigh1, 7, 128, 180224};
        const int total = 212992;
        pack_weights<<<(total + 255) / 256, 256, 0, stream>>>(
            s0, s1, s2, s3, s4, s5, total, cnt0, N1, cnt1, N2,
            (float4*)agg0, N1 * F / 4);
    }
    // sort structure: count -> scan -> fill (feature-independent)
    count2_kernel<<<(E0 + E1 + 255) / 256, 256, 0, stream>>>(
        edst0, cnt0, E0, edst1, cnt1, E1);
    exscan2_kernel<<<2, 1024, 0, stream>>>(cnt0, off0, cur0, N1, cnt1, off1, cur1, N2);
    fill2_kernel<<<(E0 + E1 + 255) / 256, 256, 0, stream>>>(
        esrc0, edst0, cur0, srcs0, dsts0, E0, esrc1, edst1, cur1, srcs1, E1);

    const uint32 LDS128 = (128 + 8) * 128 * 2;   // 34816
    const uint32 LDS256 = (256 + 8) * 128 * 2;   // 67584

    // 1+2) agg0 = segment_max(relu(h_item[srcs]@W_pool0 + b), dsts)  [fused]
    pool0_fused<<<E0 / 128, 256, LDS128, stream>>>(
        h_item, p_pool0, b_pool0, srcs0, dsts0, (int*)agg0, E0);

    // 3) h = relu(h_item[:N1]@W_self0 + agg0@W_neigh0 + bias0) -> bf16 [N1,256]
    {
        dim3 g(N1 / 128, (2 * F) / 128);
        gemm_mfma<true, true, false, 128, 128, false, false, 4><<<g, 256, LDS128, stream>>>(
            h_item, p_self0, agg0, p_neigh0, bias0, nullptr, (void*)h, 2 * F);
    }
    // 4) m1 = relu(h @ W_pool1 + b_pool1) -> bf16 [N1,256]
    {
        dim3 g(N1 / 128, (2 * F) / 128);
        gemm_mfma<true, true, false, 256, 0, true, false, 2><<<g, 256, LDS256, stream>>>(
            h, p_pool1, nullptr, nullptr, b_pool1, nullptr, (void*)m1, 2 * F);
    }
    // 5) agg1 = segment_max(m1[esrc1], edst1) -> bf16
    gather_max_kernel<256><<<(N2 + 3) / 4, 256, 0, stream>>>(m1, off1, srcs1, agg1, N2);

    // 6) out = h_item_dst + h[:N2]@W_self1 + agg1@W_neigh1 + bias1   [N2,128] fp32
    {
        dim3 g(N2 / 128, F / 128);
        gemm_mfma<false, false, true, 256, 256, true, true, 2><<<g, 256, LDS256, stream>>>(
            h, p_self1, agg1, p_neigh1, bias1, h_item_dst, d_out, F);
    }
}